// Round 1
// baseline (1053.952 us; speedup 1.0000x reference)
//
#include <hip/hip_runtime.h>
#include <cstddef>

static constexpr int kDModel = 256;
static constexpr int kDInner = 512;
static constexpr int kDState = 16;
static constexpr int kDtRank = 16;
static constexpr int kB = 16;
static constexpr int kL = 1024;
static constexpr int kTok = kB * kL;   // 16384
static constexpr int kDbcW = kDtRank + 2 * kDState;  // 48

__device__ __forceinline__ float siluf(float x) {
  return x / (1.0f + __expf(-x));
}

// C[m,n] = sum_k A[m*lda+k] * B[n*ldb+k]   (A row-major MxK, B row-major NxK -> A @ B^T)
// EPI 0: plain store to C (ld=ldc), guarded n<N
// EPI 1: split store: n<512 -> C (x buffer), n>=512 -> out2 (z buffer), both ld=512
// EPI 2: softplus(acc + bias[n]) -> C
template <int EPI>
__global__ __launch_bounds__(256) void gemm_bt_f32(
    const float* __restrict__ A, int lda,
    const float* __restrict__ B, int ldb,
    float* __restrict__ C, int ldc,
    int N, int K,
    float* __restrict__ out2,
    const float* __restrict__ bias)
{
  constexpr int BM = 64, BN = 64, BK = 16;
  __shared__ float As[BK][BM];
  __shared__ float Bs[BK][BN];
  const int m0 = blockIdx.x * BM;
  const int n0 = blockIdx.y * BN;
  const int tid = (int)threadIdx.x;
  const int tx = tid & 15;       // n-dir, 0..15
  const int ty = tid >> 4;       // m-dir, 0..15
  const int lr = tid >> 2;       // loader row 0..63
  const int lk = (tid & 3) * 4;  // loader k offset 0,4,8,12

  float acc[4][4] = {};

  for (int k0 = 0; k0 < K; k0 += BK) {
    const float4 a4 = *(const float4*)(A + (size_t)(m0 + lr) * lda + k0 + lk);
    float4 b4 = make_float4(0.f, 0.f, 0.f, 0.f);
    if (n0 + lr < N)
      b4 = *(const float4*)(B + (size_t)(n0 + lr) * ldb + k0 + lk);
    __syncthreads();
    As[lk + 0][lr] = a4.x; As[lk + 1][lr] = a4.y;
    As[lk + 2][lr] = a4.z; As[lk + 3][lr] = a4.w;
    Bs[lk + 0][lr] = b4.x; Bs[lk + 1][lr] = b4.y;
    Bs[lk + 2][lr] = b4.z; Bs[lk + 3][lr] = b4.w;
    __syncthreads();
#pragma unroll
    for (int kk = 0; kk < BK; ++kk) {
      const float4 av = *(const float4*)&As[kk][ty * 4];
      const float4 bv = *(const float4*)&Bs[kk][tx * 4];
      const float a[4] = {av.x, av.y, av.z, av.w};
      const float b[4] = {bv.x, bv.y, bv.z, bv.w};
#pragma unroll
      for (int i = 0; i < 4; ++i)
#pragma unroll
        for (int j = 0; j < 4; ++j)
          acc[i][j] = fmaf(a[i], b[j], acc[i][j]);
    }
  }

#pragma unroll
  for (int i = 0; i < 4; ++i) {
    const int m = m0 + ty * 4 + i;
#pragma unroll
    for (int j = 0; j < 4; ++j) {
      const int n = n0 + tx * 4 + j;
      float v = acc[i][j];
      if (EPI == 0) {
        if (n < N) C[(size_t)m * ldc + n] = v;
      } else if (EPI == 1) {
        if (n < kDInner) C[(size_t)m * kDInner + n] = v;
        else out2[(size_t)m * kDInner + (n - kDInner)] = v;
      } else {
        v += bias[n];
        v = fmaxf(v, 0.f) + __logf(1.f + __expf(-fabsf(v)));
        if (n < N) C[(size_t)m * ldc + n] = v;
      }
    }
  }
}

// Depthwise causal conv1d (4 taps, left pad 3) + bias + silu.
// One thread per (token, 4-channel group).
__global__ __launch_bounds__(256) void conv_silu_k(
    const float* __restrict__ x, const float* __restrict__ cw,
    const float* __restrict__ cb, float* __restrict__ xc)
{
  const int id = (int)(blockIdx.x * 256 + threadIdx.x);
  const int dq = (id & 127) * 4;      // channel group base
  const int t  = id >> 7;             // global token index = b*1024 + l
  const int l  = t & (kL - 1);

  float w[4][4];
#pragma unroll
  for (int j = 0; j < 4; ++j) {
    const float4 wt = *(const float4*)(cw + (size_t)(dq + j) * 4);
    w[j][0] = wt.x; w[j][1] = wt.y; w[j][2] = wt.z; w[j][3] = wt.w;
  }
  float r[4] = {cb[dq + 0], cb[dq + 1], cb[dq + 2], cb[dq + 3]};
#pragma unroll
  for (int k = 0; k < 4; ++k) {
    const int ll = l + k - 3;
    if (ll >= 0) {
      const float4 xv = *(const float4*)(x + (size_t)(t + k - 3) * kDInner + dq);
      r[0] = fmaf(xv.x, w[0][k], r[0]);
      r[1] = fmaf(xv.y, w[1][k], r[1]);
      r[2] = fmaf(xv.z, w[2][k], r[2]);
      r[3] = fmaf(xv.w, w[3][k], r[3]);
    }
  }
  *(float4*)(xc + (size_t)t * kDInner + dq) =
      make_float4(siluf(r[0]), siluf(r[1]), siluf(r[2]), siluf(r[3]));
}

// Fused selective scan: dA/dBu computed on the fly, y = (scan + x*D) * silu(z).
// Lane mapping: lane = c*16 + n; wave handles 4 channels x 16 states.
__global__ __launch_bounds__(256) void scan_k(
    const float* __restrict__ delta, const float* __restrict__ xc,
    const float* __restrict__ dbc,  const float* __restrict__ z,
    const float* __restrict__ A_log, const float* __restrict__ D_skip,
    float* __restrict__ y)
{
  const int gw = (int)((blockIdx.x * blockDim.x + threadIdx.x) >> 6);  // 0..2047
  const int lane = (int)(threadIdx.x & 63);
  const int n = lane & 15;
  const int c = lane >> 4;
  const int b = gw >> 7;                    // 128 waves per batch
  const int d = ((gw & 127) << 2) + c;

  const float Aval = -__expf(A_log[d * kDState + n]);
  const float Dv = D_skip[d];

  const size_t base = (size_t)b * kL * kDInner + d;
  const float* dp = delta + base;
  const float* xp = xc + base;
  const float* zp = z + base;
  const float* bp = dbc + (size_t)b * kL * kDbcW + kDtRank + n;
  float* yp = y + base;

  float h = 0.f;
  for (int l = 0; l < kL; ++l) {
    const float dl = dp[(size_t)l * kDInner];
    const float xv = xp[(size_t)l * kDInner];
    const float Bv = bp[(size_t)l * kDbcW];
    const float Cv = bp[(size_t)l * kDbcW + kDState];
    const float dA = __expf(dl * Aval);
    h = fmaf(dA, h, dl * Bv * xv);
    float ys = h * Cv;
    ys += __shfl_xor(ys, 1);
    ys += __shfl_xor(ys, 2);
    ys += __shfl_xor(ys, 4);
    ys += __shfl_xor(ys, 8);
    if (n == 0) {
      const float zv = zp[(size_t)l * kDInner];
      float yv = ys + xv * Dv;
      yv *= zv / (1.f + __expf(-zv));
      yp[(size_t)l * kDInner] = yv;
    }
  }
}

extern "C" void kernel_launch(void* const* d_in, const int* in_sizes, int n_in,
                              void* d_out, int out_size, void* d_ws, size_t ws_size,
                              hipStream_t stream) {
  (void)in_sizes; (void)n_in; (void)out_size; (void)ws_size;
  const float* token     = (const float*)d_in[0];
  const float* in_proj_w = (const float*)d_in[1];
  const float* conv_w    = (const float*)d_in[2];
  const float* conv_b    = (const float*)d_in[3];
  const float* x_proj_w  = (const float*)d_in[4];
  const float* dt_proj_w = (const float*)d_in[5];
  const float* dt_proj_b = (const float*)d_in[6];
  const float* A_log     = (const float*)d_in[7];
  const float* D_skip    = (const float*)d_in[8];
  const float* out_proj_w= (const float*)d_in[9];
  float* out = (float*)d_out;

  float* ws = (float*)d_ws;
  float* xbuf  = ws;                                    // kTok*512
  float* zbuf  = xbuf + (size_t)kTok * kDInner;         // kTok*512
  float* xcbuf = zbuf + (size_t)kTok * kDInner;         // kTok*512
  float* dbc   = xcbuf + (size_t)kTok * kDInner;        // kTok*48
  float* ybuf  = dbc + (size_t)kTok * kDbcW;            // kTok*512
  float* delta = xbuf;  // alias: x is dead after conv

  // K1: xz = token @ in_proj_w^T  -> x, z
  {
    dim3 g(kTok / 64, (2 * kDInner) / 64);
    gemm_bt_f32<1><<<g, 256, 0, stream>>>(token, kDModel, in_proj_w, kDModel,
                                          xbuf, kDInner, 2 * kDInner, kDModel,
                                          zbuf, nullptr);
  }
  // K2: depthwise conv + silu -> xc
  conv_silu_k<<<(kTok * (kDInner / 4)) / 256, 256, 0, stream>>>(xbuf, conv_w, conv_b, xcbuf);
  // K3: dbc = xc @ x_proj_w^T  (N=48)
  {
    dim3 g(kTok / 64, 1);
    gemm_bt_f32<0><<<g, 256, 0, stream>>>(xcbuf, kDInner, x_proj_w, kDInner,
                                          dbc, kDbcW, kDbcW, kDInner,
                                          nullptr, nullptr);
  }
  // K4: delta = softplus(dt @ dt_proj_w^T + b)   (dt = dbc[:, :16])
  {
    dim3 g(kTok / 64, kDInner / 64);
    gemm_bt_f32<2><<<g, 256, 0, stream>>>(dbc, kDbcW, dt_proj_w, kDtRank,
                                          delta, kDInner, kDInner, kDtRank,
                                          nullptr, dt_proj_b);
  }
  // K5: fused selective scan + skip + gate -> y
  scan_k<<<512, 256, 0, stream>>>(delta, xcbuf, dbc, zbuf, A_log, D_skip, ybuf);
  // K6: out = y @ out_proj_w^T
  {
    dim3 g(kTok / 64, kDModel / 64);
    gemm_bt_f32<0><<<g, 256, 0, stream>>>(ybuf, kDInner, out_proj_w, kDInner,
                                          out, kDModel, kDModel, kDInner,
                                          nullptr, nullptr);
  }
}

// Round 3
// 613.529 us; speedup vs baseline: 1.7179x; 1.7179x over previous
//
#include <hip/hip_runtime.h>
#include <cstddef>

static constexpr int kDModel = 256;
static constexpr int kDInner = 512;
static constexpr int kDState = 16;
static constexpr int kDtRank = 16;
static constexpr int kB = 16;
static constexpr int kL = 1024;
static constexpr int kTok = kB * kL;   // 16384
static constexpr int kDbcW = kDtRank + 2 * kDState;  // 48
static constexpr int kT = 64;          // chunk length
static constexpr int kG = kL / kT;     // 16 chunks per sequence

__device__ __forceinline__ float siluf(float x) {
  return x / (1.0f + __expf(-x));
}

// C[m,n] = sum_k A[m*lda+k] * B[n*ldb+k]   (A row-major MxK, B row-major NxK -> A @ B^T)
// EPI 0: plain store to C (ld=ldc), guarded n<N
// EPI 1: split store: n<512 -> C (x buffer), n>=512 -> out2 (z buffer), both ld=512
// EPI 2: softplus(acc + bias[n]) -> C
template <int EPI>
__global__ __launch_bounds__(256) void gemm_bt_f32(
    const float* __restrict__ A, int lda,
    const float* __restrict__ B, int ldb,
    float* __restrict__ C, int ldc,
    int N, int K,
    float* __restrict__ out2,
    const float* __restrict__ bias)
{
  constexpr int BM = 64, BN = 64, BK = 16;
  __shared__ float As[BK][BM];
  __shared__ float Bs[BK][BN];
  const int m0 = blockIdx.x * BM;
  const int n0 = blockIdx.y * BN;
  const int tid = (int)threadIdx.x;
  const int tx = tid & 15;       // n-dir, 0..15
  const int ty = tid >> 4;       // m-dir, 0..15
  const int lr = tid >> 2;       // loader row 0..63
  const int lk = (tid & 3) * 4;  // loader k offset 0,4,8,12

  float acc[4][4] = {};

  for (int k0 = 0; k0 < K; k0 += BK) {
    const float4 a4 = *(const float4*)(A + (size_t)(m0 + lr) * lda + k0 + lk);
    float4 b4 = make_float4(0.f, 0.f, 0.f, 0.f);
    if (n0 + lr < N)
      b4 = *(const float4*)(B + (size_t)(n0 + lr) * ldb + k0 + lk);
    __syncthreads();
    As[lk + 0][lr] = a4.x; As[lk + 1][lr] = a4.y;
    As[lk + 2][lr] = a4.z; As[lk + 3][lr] = a4.w;
    Bs[lk + 0][lr] = b4.x; Bs[lk + 1][lr] = b4.y;
    Bs[lk + 2][lr] = b4.z; Bs[lk + 3][lr] = b4.w;
    __syncthreads();
#pragma unroll
    for (int kk = 0; kk < BK; ++kk) {
      const float4 av = *(const float4*)&As[kk][ty * 4];
      const float4 bv = *(const float4*)&Bs[kk][tx * 4];
      const float a[4] = {av.x, av.y, av.z, av.w};
      const float b[4] = {bv.x, bv.y, bv.z, bv.w};
#pragma unroll
      for (int i = 0; i < 4; ++i)
#pragma unroll
        for (int j = 0; j < 4; ++j)
          acc[i][j] = fmaf(a[i], b[j], acc[i][j]);
    }
  }

#pragma unroll
  for (int i = 0; i < 4; ++i) {
    const int m = m0 + ty * 4 + i;
#pragma unroll
    for (int j = 0; j < 4; ++j) {
      const int n = n0 + tx * 4 + j;
      float v = acc[i][j];
      if (EPI == 0) {
        if (n < N) C[(size_t)m * ldc + n] = v;
      } else if (EPI == 1) {
        if (n < kDInner) C[(size_t)m * kDInner + n] = v;
        else out2[(size_t)m * kDInner + (n - kDInner)] = v;
      } else {
        v += bias[n];
        v = fmaxf(v, 0.f) + __logf(1.f + __expf(-fabsf(v)));
        if (n < N) C[(size_t)m * ldc + n] = v;
      }
    }
  }
}

// Depthwise causal conv1d (4 taps, left pad 3) + bias + silu.
__global__ __launch_bounds__(256) void conv_silu_k(
    const float* __restrict__ x, const float* __restrict__ cw,
    const float* __restrict__ cb, float* __restrict__ xc)
{
  const int id = (int)(blockIdx.x * 256 + threadIdx.x);
  const int dq = (id & 127) * 4;      // channel group base
  const int t  = id >> 7;             // global token index = b*1024 + l
  const int l  = t & (kL - 1);

  float w[4][4];
#pragma unroll
  for (int j = 0; j < 4; ++j) {
    const float4 wt = *(const float4*)(cw + (size_t)(dq + j) * 4);
    w[j][0] = wt.x; w[j][1] = wt.y; w[j][2] = wt.z; w[j][3] = wt.w;
  }
  float r[4] = {cb[dq + 0], cb[dq + 1], cb[dq + 2], cb[dq + 3]};
#pragma unroll
  for (int k = 0; k < 4; ++k) {
    const int ll = l + k - 3;
    if (ll >= 0) {
      const float4 xv = *(const float4*)(x + (size_t)(t + k - 3) * kDInner + dq);
      r[0] = fmaf(xv.x, w[0][k], r[0]);
      r[1] = fmaf(xv.y, w[1][k], r[1]);
      r[2] = fmaf(xv.z, w[2][k], r[2]);
      r[3] = fmaf(xv.w, w[3][k], r[3]);
    }
  }
  *(float4*)(xc + (size_t)t * kDInner + dq) =
      make_float4(siluf(r[0]), siluf(r[1]), siluf(r[2]), siluf(r[3]));
}

// ---------------- Chunked selective scan (3 passes) ----------------
// Wave mapping (S1/S3): lane = ch*16 + n; wave handles 4 channels x 16 states
// over ONE chunk of kT=64 timesteps.
// gw = ((b*kG + c) << 7) | dgroup,  d = dgroup*4 + ch.
// Summary layout: idx = ((b*512 + d)*kG + c)*16 + n.

// S1: local scan from h=0; emit P = prod(dA) and h_loc (chunk-final state).
__global__ __launch_bounds__(256) void scan_part1(
    const float* __restrict__ delta, const float* __restrict__ xc,
    const float* __restrict__ dbc,  const float* __restrict__ A_log,
    float* __restrict__ Pbuf, float* __restrict__ hloc)
{
  const int gw = (int)((blockIdx.x * 256 + threadIdx.x) >> 6);  // 0..32767
  const int lane = (int)(threadIdx.x & 63);
  const int n = lane & 15;
  const int ch = lane >> 4;
  const int dgroup = gw & 127;
  const int c = (gw >> 7) & (kG - 1);
  const int b = gw >> 11;
  const int d = dgroup * 4 + ch;

  const float Aval = -__expf(A_log[d * kDState + n]);
  const size_t base = ((size_t)b * kL + (size_t)c * kT) * kDInner + d;
  const float* dp = delta + base;
  const float* xp = xc + base;
  const float* bp = dbc + ((size_t)b * kL + (size_t)c * kT) * kDbcW + kDtRank + n;

  float h = 0.f, P = 1.f;
#pragma unroll 4
  for (int l = 0; l < kT; ++l) {
    const float dl = dp[(size_t)l * kDInner];
    const float xv = xp[(size_t)l * kDInner];
    const float Bv = bp[(size_t)l * kDbcW];
    const float dA = __expf(dl * Aval);
    h = fmaf(dA, h, dl * Bv * xv);
    P *= dA;
  }
  const size_t o = (((size_t)(b * kDInner + d) * kG) + c) * kDState + n;
  Pbuf[o] = P;
  hloc[o] = h;
}

// S2: inter-chunk scan (16 steps) per (b,d,n) -> chunk entry states h_in.
__global__ __launch_bounds__(256) void scan_part2(
    const float* __restrict__ Pbuf, const float* __restrict__ hloc,
    float* __restrict__ hin)
{
  const int t = (int)(blockIdx.x * 256 + threadIdx.x);  // (b*512+d)*16 + n
  const size_t base = (size_t)(t >> 4) * (kG * kDState) + (t & 15);
  float carry = 0.f;
#pragma unroll
  for (int c = 0; c < kG; ++c) {
    const size_t idx = base + (size_t)c * kDState;
    hin[idx] = carry;
    carry = fmaf(Pbuf[idx], carry, hloc[idx]);
  }
}

// S3: local scan from h_in; y = <h,C> + x*D, gated by silu(z).
__global__ __launch_bounds__(256) void scan_part3(
    const float* __restrict__ delta, const float* __restrict__ xc,
    const float* __restrict__ dbc,  const float* __restrict__ z,
    const float* __restrict__ A_log, const float* __restrict__ D_skip,
    const float* __restrict__ hin,  float* __restrict__ y)
{
  const int gw = (int)((blockIdx.x * 256 + threadIdx.x) >> 6);
  const int lane = (int)(threadIdx.x & 63);
  const int n = lane & 15;
  const int ch = lane >> 4;
  const int dgroup = gw & 127;
  const int c = (gw >> 7) & (kG - 1);
  const int b = gw >> 11;
  const int d = dgroup * 4 + ch;

  const float Aval = -__expf(A_log[d * kDState + n]);
  const float Dv = D_skip[d];
  const size_t base = ((size_t)b * kL + (size_t)c * kT) * kDInner + d;
  const float* dp = delta + base;
  const float* xp = xc + base;
  const float* zp = z + base;
  float* yp = y + base;
  const float* bp = dbc + ((size_t)b * kL + (size_t)c * kT) * kDbcW + kDtRank + n;

  float h = hin[(((size_t)(b * kDInner + d) * kG) + c) * kDState + n];
#pragma unroll 4
  for (int l = 0; l < kT; ++l) {
    const float dl = dp[(size_t)l * kDInner];
    const float xv = xp[(size_t)l * kDInner];
    const float Bv = bp[(size_t)l * kDbcW];
    const float Cv = bp[(size_t)l * kDbcW + kDState];
    const float dA = __expf(dl * Aval);
    h = fmaf(dA, h, dl * Bv * xv);
    float ys = h * Cv;
    ys += __shfl_xor(ys, 1);
    ys += __shfl_xor(ys, 2);
    ys += __shfl_xor(ys, 4);
    ys += __shfl_xor(ys, 8);
    if (n == 0) {
      const float zv = zp[(size_t)l * kDInner];
      float yv = ys + xv * Dv;
      yv *= zv / (1.f + __expf(-zv));
      yp[(size_t)l * kDInner] = yv;
    }
  }
}

extern "C" void kernel_launch(void* const* d_in, const int* in_sizes, int n_in,
                              void* d_out, int out_size, void* d_ws, size_t ws_size,
                              hipStream_t stream) {
  (void)in_sizes; (void)n_in; (void)out_size; (void)ws_size;
  const float* token     = (const float*)d_in[0];
  const float* in_proj_w = (const float*)d_in[1];
  const float* conv_w    = (const float*)d_in[2];
  const float* conv_b    = (const float*)d_in[3];
  const float* x_proj_w  = (const float*)d_in[4];
  const float* dt_proj_w = (const float*)d_in[5];
  const float* dt_proj_b = (const float*)d_in[6];
  const float* A_log     = (const float*)d_in[7];
  const float* D_skip    = (const float*)d_in[8];
  const float* out_proj_w= (const float*)d_in[9];
  float* out = (float*)d_out;

  float* ws = (float*)d_ws;
  float* xbuf  = ws;                                    // kTok*512
  float* zbuf  = xbuf + (size_t)kTok * kDInner;         // kTok*512
  float* xcbuf = zbuf + (size_t)kTok * kDInner;         // kTok*512
  float* dbc   = xcbuf + (size_t)kTok * kDInner;        // kTok*48
  float* ybuf  = dbc + (size_t)kTok * kDbcW;            // kTok*512
  float* hin   = ybuf + (size_t)kTok * kDInner;         // B*D*G*N = 2M floats
  float* delta = xbuf;   // alias: x is dead after conv
  // P/hloc die after S2, before any y store -> alias them onto ybuf.
  float* Pbuf  = ybuf;                                  // 2M floats
  float* hloc  = ybuf + (size_t)kB * kDInner * kG * kDState;  // 2M floats

  // K1: xz = token @ in_proj_w^T  -> x, z
  {
    dim3 g(kTok / 64, (2 * kDInner) / 64);
    gemm_bt_f32<1><<<g, 256, 0, stream>>>(token, kDModel, in_proj_w, kDModel,
                                          xbuf, kDInner, 2 * kDInner, kDModel,
                                          zbuf, nullptr);
  }
  // K2: depthwise conv + silu -> xc
  conv_silu_k<<<(kTok * (kDInner / 4)) / 256, 256, 0, stream>>>(xbuf, conv_w, conv_b, xcbuf);
  // K3: dbc = xc @ x_proj_w^T  (N=48)
  {
    dim3 g(kTok / 64, 1);
    gemm_bt_f32<0><<<g, 256, 0, stream>>>(xcbuf, kDInner, x_proj_w, kDInner,
                                          dbc, kDbcW, kDbcW, kDInner,
                                          nullptr, nullptr);
  }
  // K4: delta = softplus(dt @ dt_proj_w^T + b)   (dt = dbc[:, :16])
  {
    dim3 g(kTok / 64, kDInner / 64);
    gemm_bt_f32<2><<<g, 256, 0, stream>>>(dbc, kDbcW, dt_proj_w, kDtRank,
                                          delta, kDInner, kDInner, kDtRank,
                                          nullptr, dt_proj_b);
  }
  // S1/S2/S3: chunked selective scan
  scan_part1<<<(kB * kG * 128) / 4, 256, 0, stream>>>(delta, xcbuf, dbc, A_log,
                                                      Pbuf, hloc);
  scan_part2<<<(kB * kDInner * kDState) / 256, 256, 0, stream>>>(Pbuf, hloc, hin);
  scan_part3<<<(kB * kG * 128) / 4, 256, 0, stream>>>(delta, xcbuf, dbc, zbuf,
                                                      A_log, D_skip, hin, ybuf);
  // K6: out = y @ out_proj_w^T
  {
    dim3 g(kTok / 64, kDModel / 64);
    gemm_bt_f32<0><<<g, 256, 0, stream>>>(ybuf, kDInner, out_proj_w, kDInner,
                                          out, kDModel, kDModel, kDInner,
                                          nullptr, nullptr);
  }
}

// Round 5
// 418.442 us; speedup vs baseline: 2.5188x; 1.4662x over previous
//
#include <hip/hip_runtime.h>
#include <cstddef>

static constexpr int kDModel = 256;
static constexpr int kDInner = 512;
static constexpr int kDState = 16;
static constexpr int kDtRank = 16;
static constexpr int kB = 16;
static constexpr int kL = 1024;
static constexpr int kTok = kB * kL;   // 16384
static constexpr int kDbcW = kDtRank + 2 * kDState;  // 48
static constexpr int kT = 64;          // chunk length
static constexpr int kG = kL / kT;     // 16 chunks per sequence

__device__ __forceinline__ float siluf(float x) {
  return x / (1.0f + __expf(-x));
}

// C[m,n] = sum_k A[m*lda+k] * B[n*ldb+k]   (A row-major MxK, B row-major NxK -> A @ B^T)
// EPI 0: plain store to C (ld=ldc), guarded n<N
// EPI 1: split store: n<512 -> C (x buffer), n>=512 -> out2 (z buffer), both ld=512
// EPI 2: softplus(acc + bias[n]) -> C
template <int EPI>
__global__ __launch_bounds__(256) void gemm_bt_f32(
    const float* __restrict__ A, int lda,
    const float* __restrict__ B, int ldb,
    float* __restrict__ C, int ldc,
    int N, int K,
    float* __restrict__ out2,
    const float* __restrict__ bias)
{
  constexpr int BM = 64, BN = 64, BK = 16;
  __shared__ float As[BK][BM];
  __shared__ float Bs[BK][BN];
  const int m0 = blockIdx.x * BM;
  const int n0 = blockIdx.y * BN;
  const int tid = (int)threadIdx.x;
  const int tx = tid & 15;       // n-dir, 0..15
  const int ty = tid >> 4;       // m-dir, 0..15
  const int lr = tid >> 2;       // loader row 0..63
  const int lk = (tid & 3) * 4;  // loader k offset 0,4,8,12

  float acc[4][4] = {};

  for (int k0 = 0; k0 < K; k0 += BK) {
    const float4 a4 = *(const float4*)(A + (size_t)(m0 + lr) * lda + k0 + lk);
    float4 b4 = make_float4(0.f, 0.f, 0.f, 0.f);
    if (n0 + lr < N)
      b4 = *(const float4*)(B + (size_t)(n0 + lr) * ldb + k0 + lk);
    __syncthreads();
    As[lk + 0][lr] = a4.x; As[lk + 1][lr] = a4.y;
    As[lk + 2][lr] = a4.z; As[lk + 3][lr] = a4.w;
    Bs[lk + 0][lr] = b4.x; Bs[lk + 1][lr] = b4.y;
    Bs[lk + 2][lr] = b4.z; Bs[lk + 3][lr] = b4.w;
    __syncthreads();
#pragma unroll
    for (int kk = 0; kk < BK; ++kk) {
      const float4 av = *(const float4*)&As[kk][ty * 4];
      const float4 bv = *(const float4*)&Bs[kk][tx * 4];
      const float a[4] = {av.x, av.y, av.z, av.w};
      const float b[4] = {bv.x, bv.y, bv.z, bv.w};
#pragma unroll
      for (int i = 0; i < 4; ++i)
#pragma unroll
        for (int j = 0; j < 4; ++j)
          acc[i][j] = fmaf(a[i], b[j], acc[i][j]);
    }
  }

#pragma unroll
  for (int i = 0; i < 4; ++i) {
    const int m = m0 + ty * 4 + i;
#pragma unroll
    for (int j = 0; j < 4; ++j) {
      const int n = n0 + tx * 4 + j;
      float v = acc[i][j];
      if (EPI == 0) {
        if (n < N) C[(size_t)m * ldc + n] = v;
      } else if (EPI == 1) {
        if (n < kDInner) C[(size_t)m * kDInner + n] = v;
        else out2[(size_t)m * kDInner + (n - kDInner)] = v;
      } else {
        v += bias[n];
        v = fmaxf(v, 0.f) + __logf(1.f + __expf(-fabsf(v)));
        if (n < N) C[(size_t)m * ldc + n] = v;
      }
    }
  }
}

// Depthwise causal conv1d (4 taps, left pad 3) + bias + silu.
__global__ __launch_bounds__(256) void conv_silu_k(
    const float* __restrict__ x, const float* __restrict__ cw,
    const float* __restrict__ cb, float* __restrict__ xc)
{
  const int id = (int)(blockIdx.x * 256 + threadIdx.x);
  const int dq = (id & 127) * 4;      // channel group base
  const int t  = id >> 7;             // global token index = b*1024 + l
  const int l  = t & (kL - 1);

  float w[4][4];
#pragma unroll
  for (int j = 0; j < 4; ++j) {
    const float4 wt = *(const float4*)(cw + (size_t)(dq + j) * 4);
    w[j][0] = wt.x; w[j][1] = wt.y; w[j][2] = wt.z; w[j][3] = wt.w;
  }
  float r[4] = {cb[dq + 0], cb[dq + 1], cb[dq + 2], cb[dq + 3]};
#pragma unroll
  for (int k = 0; k < 4; ++k) {
    const int ll = l + k - 3;
    if (ll >= 0) {
      const float4 xv = *(const float4*)(x + (size_t)(t + k - 3) * kDInner + dq);
      r[0] = fmaf(xv.x, w[0][k], r[0]);
      r[1] = fmaf(xv.y, w[1][k], r[1]);
      r[2] = fmaf(xv.z, w[2][k], r[2]);
      r[3] = fmaf(xv.w, w[3][k], r[3]);
    }
  }
  *(float4*)(xc + (size_t)t * kDInner + dq) =
      make_float4(siluf(r[0]), siluf(r[1]), siluf(r[2]), siluf(r[3]));
}

// ---------------- Chunked selective scan (3 passes), lane = channel d ----------------
// Wave = 64 consecutive channels; each lane holds all 16 states in registers.
// delta/x/z/y accesses are coalesced 64-wide; B/C are wave-uniform -> s_load
// (gw hoisted to SGPR via readfirstlane). No cross-lane ops at all.
// Summary layout (d-contiguous for coalescing): idx = ((b*kG + c)*16 + n)*512 + d.

// S1: local scan from h=0; emit P = exp2(A2 * sum(delta)) and h_loc.
__global__ __launch_bounds__(256) void scan_part1(
    const float* __restrict__ delta, const float* __restrict__ xc,
    const float* __restrict__ dbc,  const float* __restrict__ A_log,
    float* __restrict__ Pbuf, float* __restrict__ hloc)
{
  const int tid = (int)(blockIdx.x * 256 + threadIdx.x);
  const int lane = tid & 63;
  const int gw = __builtin_amdgcn_readfirstlane(tid >> 6);  // 0..2047, SGPR
  const int dg = gw & 7;
  const int c  = (gw >> 3) & (kG - 1);
  const int b  = gw >> 7;
  const int d  = dg * 64 + lane;
  const int t0 = b * kL + c * kT;

  float A2[kDState], h[kDState];
#pragma unroll
  for (int n = 0; n < kDState; ++n) {
    A2[n] = -__expf(A_log[d * kDState + n]) * 1.44269504088896f;
    h[n] = 0.f;
  }
  const float* dp = delta + (size_t)t0 * kDInner + d;
  const float* xp = xc + (size_t)t0 * kDInner + d;
  float sd = 0.f;
#pragma unroll 2
  for (int l = 0; l < kT; ++l) {
    const float dl = dp[(size_t)l * kDInner];
    const float xv = xp[(size_t)l * kDInner];
    const float* bp = dbc + (size_t)(t0 + l) * kDbcW + kDtRank;  // uniform
    const float s = dl * xv;
    sd += dl;
#pragma unroll
    for (int n = 0; n < kDState; ++n) {
      const float dA = __builtin_amdgcn_exp2f(dl * A2[n]);
      h[n] = fmaf(dA, h[n], s * bp[n]);
    }
  }
  const size_t o0 = (size_t)((b * kG + c) * kDState) * kDInner + d;
#pragma unroll
  for (int n = 0; n < kDState; ++n) {
    Pbuf[o0 + (size_t)n * kDInner] = __builtin_amdgcn_exp2f(A2[n] * sd);
    hloc[o0 + (size_t)n * kDInner] = h[n];
  }
}

// S2: inter-chunk scan (kG steps) per (b,d,n) -> chunk entry states h_in.
__global__ __launch_bounds__(256) void scan_part2(
    const float* __restrict__ Pbuf, const float* __restrict__ hloc,
    float* __restrict__ hin)
{
  const int t = (int)(blockIdx.x * 256 + threadIdx.x);  // 0..131071
  const int d = t & (kDInner - 1);
  const int n = (t >> 9) & (kDState - 1);
  const int b = t >> 13;
  float carry = 0.f;
#pragma unroll
  for (int c = 0; c < kG; ++c) {
    const size_t idx = (size_t)((b * kG + c) * kDState + n) * kDInner + d;
    hin[idx] = carry;
    carry = fmaf(Pbuf[idx], carry, hloc[idx]);
  }
}

// S3: local scan from h_in; y = <h,C> + x*D, gated by silu(z). Fully in-lane.
__global__ __launch_bounds__(256) void scan_part3(
    const float* __restrict__ delta, const float* __restrict__ xc,
    const float* __restrict__ dbc,  const float* __restrict__ z,
    const float* __restrict__ A_log, const float* __restrict__ D_skip,
    const float* __restrict__ hin,  float* __restrict__ y)
{
  const int tid = (int)(blockIdx.x * 256 + threadIdx.x);
  const int lane = tid & 63;
  const int gw = __builtin_amdgcn_readfirstlane(tid >> 6);
  const int dg = gw & 7;
  const int c  = (gw >> 3) & (kG - 1);
  const int b  = gw >> 7;
  const int d  = dg * 64 + lane;
  const int t0 = b * kL + c * kT;

  const size_t o0 = (size_t)((b * kG + c) * kDState) * kDInner + d;
  float A2[kDState], h[kDState];
#pragma unroll
  for (int n = 0; n < kDState; ++n) {
    A2[n] = -__expf(A_log[d * kDState + n]) * 1.44269504088896f;
    h[n] = hin[o0 + (size_t)n * kDInner];
  }
  const float Dv = D_skip[d];
  const float* dp = delta + (size_t)t0 * kDInner + d;
  const float* xp = xc + (size_t)t0 * kDInner + d;
  const float* zp = z + (size_t)t0 * kDInner + d;
  float* yp = y + (size_t)t0 * kDInner + d;
#pragma unroll 2
  for (int l = 0; l < kT; ++l) {
    const float dl = dp[(size_t)l * kDInner];
    const float xv = xp[(size_t)l * kDInner];
    const float zv = zp[(size_t)l * kDInner];
    const float* bp = dbc + (size_t)(t0 + l) * kDbcW + kDtRank;  // uniform
    const float s = dl * xv;
    float yv = 0.f;
#pragma unroll
    for (int n = 0; n < kDState; ++n) {
      const float dA = __builtin_amdgcn_exp2f(dl * A2[n]);
      h[n] = fmaf(dA, h[n], s * bp[n]);
      yv = fmaf(h[n], bp[kDState + n], yv);
    }
    yv = fmaf(xv, Dv, yv);
    yv *= zv / (1.f + __expf(-zv));
    yp[(size_t)l * kDInner] = yv;
  }
}

extern "C" void kernel_launch(void* const* d_in, const int* in_sizes, int n_in,
                              void* d_out, int out_size, void* d_ws, size_t ws_size,
                              hipStream_t stream) {
  (void)in_sizes; (void)n_in; (void)out_size; (void)ws_size;
  const float* token     = (const float*)d_in[0];
  const float* in_proj_w = (const float*)d_in[1];
  const float* conv_w    = (const float*)d_in[2];
  const float* conv_b    = (const float*)d_in[3];
  const float* x_proj_w  = (const float*)d_in[4];
  const float* dt_proj_w = (const float*)d_in[5];
  const float* dt_proj_b = (const float*)d_in[6];
  const float* A_log     = (const float*)d_in[7];
  const float* D_skip    = (const float*)d_in[8];
  const float* out_proj_w= (const float*)d_in[9];
  float* out = (float*)d_out;

  float* ws = (float*)d_ws;
  float* xbuf  = ws;                                    // kTok*512
  float* zbuf  = xbuf + (size_t)kTok * kDInner;         // kTok*512
  float* xcbuf = zbuf + (size_t)kTok * kDInner;         // kTok*512
  float* dbc   = xcbuf + (size_t)kTok * kDInner;        // kTok*48
  float* ybuf  = dbc + (size_t)kTok * kDbcW;            // kTok*512
  float* hin   = ybuf + (size_t)kTok * kDInner;         // B*G*N*D = 2M floats
  float* delta = xbuf;   // alias: x is dead after conv
  // P/hloc die after S2, before any y store -> alias them onto ybuf.
  float* Pbuf  = ybuf;                                  // 2M floats
  float* hloc  = ybuf + (size_t)kB * kG * kDState * kDInner;  // 2M floats

  // K1: xz = token @ in_proj_w^T  -> x, z
  {
    dim3 g(kTok / 64, (2 * kDInner) / 64);
    gemm_bt_f32<1><<<g, 256, 0, stream>>>(token, kDModel, in_proj_w, kDModel,
                                          xbuf, kDInner, 2 * kDInner, kDModel,
                                          zbuf, nullptr);
  }
  // K2: depthwise conv + silu -> xc
  conv_silu_k<<<(kTok * (kDInner / 4)) / 256, 256, 0, stream>>>(xbuf, conv_w, conv_b, xcbuf);
  // K3: dbc = xc @ x_proj_w^T  (N=48)
  {
    dim3 g(kTok / 64, 1);
    gemm_bt_f32<0><<<g, 256, 0, stream>>>(xcbuf, kDInner, x_proj_w, kDInner,
                                          dbc, kDbcW, kDbcW, kDInner,
                                          nullptr, nullptr);
  }
  // K4: delta = softplus(dt @ dt_proj_w^T + b)   (dt = dbc[:, :16])
  {
    dim3 g(kTok / 64, kDInner / 64);
    gemm_bt_f32<2><<<g, 256, 0, stream>>>(dbc, kDbcW, dt_proj_w, kDtRank,
                                          delta, kDInner, kDInner, kDtRank,
                                          nullptr, dt_proj_b);
  }
  // S1/S2/S3: chunked selective scan (lane = channel)
  scan_part1<<<(kB * kG * 8) / 4, 256, 0, stream>>>(delta, xcbuf, dbc, A_log,
                                                    Pbuf, hloc);
  scan_part2<<<(kB * kDInner * kDState) / 256, 256, 0, stream>>>(Pbuf, hloc, hin);
  scan_part3<<<(kB * kG * 8) / 4, 256, 0, stream>>>(delta, xcbuf, dbc, zbuf,
                                                    A_log, D_skip, hin, ybuf);
  // K6: out = y @ out_proj_w^T
  {
    dim3 g(kTok / 64, kDModel / 64);
    gemm_bt_f32<0><<<g, 256, 0, stream>>>(ybuf, kDInner, out_proj_w, kDInner,
                                          out, kDModel, kDModel, kDInner,
                                          nullptr, nullptr);
  }
}

// Round 8
// 301.344 us; speedup vs baseline: 3.4975x; 1.3886x over previous
//
#include <hip/hip_runtime.h>
#include <cstddef>

static constexpr int kDModel = 256;
static constexpr int kDInner = 512;
static constexpr int kDState = 16;
static constexpr int kDtRank = 16;
static constexpr int kB = 16;
static constexpr int kL = 1024;
static constexpr int kTok = kB * kL;   // 16384
static constexpr int kDbcW = kDtRank + 2 * kDState;  // 48
static constexpr int kT = 64;          // chunk length
static constexpr int kG = kL / kT;     // 16 chunks per sequence

typedef __attribute__((ext_vector_type(8))) short short8;
typedef __attribute__((ext_vector_type(4))) float f32x4;

__device__ __forceinline__ float siluf(float x) {
  return x / (1.0f + __expf(-x));
}

// Split two fp32 into packed bf16 hi (truncation) and bf16 lo (residual).
// h = [bf16(b)|bf16(a)], l likewise for the residuals. Residual error ~2^-16.
__device__ __forceinline__ void split2(float a, float b, unsigned& h, unsigned& l) {
  const unsigned ua = __float_as_uint(a), ub = __float_as_uint(b);
  const unsigned ha = ua & 0xffff0000u, hb = ub & 0xffff0000u;
  h = (ha >> 16) | hb;
  const float la = a - __uint_as_float(ha);
  const float lb = b - __uint_as_float(hb);
  l = (__float_as_uint(la) >> 16) | (__float_as_uint(lb) & 0xffff0000u);
}

// ---------------- bf16-split MFMA GEMM:  C[m,n] = sum_k A[m,k]*B[n,k] ----------------
// A: MxK f32 row-major, B: NxK f32 row-major. Tile 128x64, BK=32, 4 waves (2x2),
// wave tile 64x32 = 4x2 frags of 16x16 via mfma_f32_16x16x32_bf16.
// Split product: Ah*Bh + Ah*Bl + Al*Bh  (error ~2^-16 relative, ~fp32 quality).
// EPI 0: C[m*ldc+n]. EPI 1: n<512 -> C (x), else -> out2 (z), both ld=512.
template <int EPI>
__global__ __launch_bounds__(256) void gemm_bt_mfma(
    const float* __restrict__ A, int lda,
    const float* __restrict__ B, int ldb,
    float* __restrict__ C, int ldc, int K,
    float* __restrict__ out2)
{
  __shared__ __align__(16) unsigned short Ah[128][40];  // K-dim padded 32->40: 2-way banks
  __shared__ __align__(16) unsigned short Al[128][40];
  __shared__ __align__(16) unsigned short Bh[64][40];
  __shared__ __align__(16) unsigned short Bl[64][40];

  const int tid = (int)threadIdx.x;
  const int m0 = blockIdx.x * 128;
  const int n0 = blockIdx.y * 64;
  const int lane = tid & 63;
  const int w = tid >> 6, wm = w >> 1, wn = w & 1;
  const int fr = lane & 15;          // row (A) / col (B,D) within frag
  const int ko = (lane >> 4) * 8;    // k offset within BK=32

  const int ar = tid >> 1, ak = (tid & 1) * 16;   // A loader: row, k-offset
  const int br = tid & 63, bk = (tid >> 6) * 8;   // B loader

  f32x4 acc[4][2];
#pragma unroll
  for (int i = 0; i < 4; ++i)
#pragma unroll
    for (int j = 0; j < 2; ++j) acc[i][j] = (f32x4){0.f, 0.f, 0.f, 0.f};

  for (int k0 = 0; k0 < K; k0 += 32) {
    const float* Ap = A + (size_t)(m0 + ar) * lda + k0 + ak;
    const float4 a0 = *(const float4*)(Ap);
    const float4 a1 = *(const float4*)(Ap + 4);
    const float4 a2 = *(const float4*)(Ap + 8);
    const float4 a3 = *(const float4*)(Ap + 12);
    const float* Bp = B + (size_t)(n0 + br) * ldb + k0 + bk;
    const float4 b0 = *(const float4*)(Bp);
    const float4 b1 = *(const float4*)(Bp + 4);
    __syncthreads();  // previous iter's frag reads done
    uint4 h, l;
    split2(a0.x, a0.y, h.x, l.x); split2(a0.z, a0.w, h.y, l.y);
    split2(a1.x, a1.y, h.z, l.z); split2(a1.z, a1.w, h.w, l.w);
    *(uint4*)&Ah[ar][ak] = h; *(uint4*)&Al[ar][ak] = l;
    split2(a2.x, a2.y, h.x, l.x); split2(a2.z, a2.w, h.y, l.y);
    split2(a3.x, a3.y, h.z, l.z); split2(a3.z, a3.w, h.w, l.w);
    *(uint4*)&Ah[ar][ak + 8] = h; *(uint4*)&Al[ar][ak + 8] = l;
    split2(b0.x, b0.y, h.x, l.x); split2(b0.z, b0.w, h.y, l.y);
    split2(b1.x, b1.y, h.z, l.z); split2(b1.z, b1.w, h.w, l.w);
    *(uint4*)&Bh[br][bk] = h; *(uint4*)&Bl[br][bk] = l;
    __syncthreads();

    short8 ah[4], al[4], bh[2], bl[2];
#pragma unroll
    for (int mi = 0; mi < 4; ++mi) {
      ah[mi] = *(const short8*)&Ah[wm * 64 + mi * 16 + fr][ko];
      al[mi] = *(const short8*)&Al[wm * 64 + mi * 16 + fr][ko];
    }
#pragma unroll
    for (int ni = 0; ni < 2; ++ni) {
      bh[ni] = *(const short8*)&Bh[wn * 32 + ni * 16 + fr][ko];
      bl[ni] = *(const short8*)&Bl[wn * 32 + ni * 16 + fr][ko];
    }
#pragma unroll
    for (int mi = 0; mi < 4; ++mi)
#pragma unroll
      for (int ni = 0; ni < 2; ++ni) {
        acc[mi][ni] = __builtin_amdgcn_mfma_f32_16x16x32_bf16(ah[mi], bh[ni], acc[mi][ni], 0, 0, 0);
        acc[mi][ni] = __builtin_amdgcn_mfma_f32_16x16x32_bf16(ah[mi], bl[ni], acc[mi][ni], 0, 0, 0);
        acc[mi][ni] = __builtin_amdgcn_mfma_f32_16x16x32_bf16(al[mi], bh[ni], acc[mi][ni], 0, 0, 0);
      }
  }

  float* Cb;
  int nbase, ldout;
  if (EPI == 1) {
    Cb = (n0 < kDInner) ? C : out2;
    nbase = (n0 & (kDInner - 1)) + wn * 32 + fr;
    ldout = kDInner;
  } else {
    Cb = C;
    nbase = n0 + wn * 32 + fr;
    ldout = ldc;
  }
#pragma unroll
  for (int mi = 0; mi < 4; ++mi) {
    const int mrow = m0 + wm * 64 + mi * 16 + (lane >> 4) * 4;
#pragma unroll
    for (int ni = 0; ni < 2; ++ni)
#pragma unroll
      for (int r = 0; r < 4; ++r)
        Cb[(size_t)(mrow + r) * ldout + nbase + ni * 16] = acc[mi][ni][r];
  }
}

// C[m,n] = sum_k A[m*lda+k] * B[n*ldb+k]  (fp32 VALU path, kept for small GEMMs)
// EPI 0: plain store. EPI 2: softplus(acc + bias[n]).
template <int EPI>
__global__ __launch_bounds__(256) void gemm_bt_f32(
    const float* __restrict__ A, int lda,
    const float* __restrict__ B, int ldb,
    float* __restrict__ C, int ldc,
    int N, int K,
    float* __restrict__ out2,
    const float* __restrict__ bias)
{
  constexpr int BM = 64, BN = 64, BK = 16;
  __shared__ float As[BK][BM];
  __shared__ float Bs[BK][BN];
  const int m0 = blockIdx.x * BM;
  const int n0 = blockIdx.y * BN;
  const int tid = (int)threadIdx.x;
  const int tx = tid & 15;
  const int ty = tid >> 4;
  const int lr = tid >> 2;
  const int lk = (tid & 3) * 4;

  float acc[4][4] = {};

  for (int k0 = 0; k0 < K; k0 += BK) {
    const float4 a4 = *(const float4*)(A + (size_t)(m0 + lr) * lda + k0 + lk);
    float4 b4 = make_float4(0.f, 0.f, 0.f, 0.f);
    if (n0 + lr < N)
      b4 = *(const float4*)(B + (size_t)(n0 + lr) * ldb + k0 + lk);
    __syncthreads();
    As[lk + 0][lr] = a4.x; As[lk + 1][lr] = a4.y;
    As[lk + 2][lr] = a4.z; As[lk + 3][lr] = a4.w;
    Bs[lk + 0][lr] = b4.x; Bs[lk + 1][lr] = b4.y;
    Bs[lk + 2][lr] = b4.z; Bs[lk + 3][lr] = b4.w;
    __syncthreads();
#pragma unroll
    for (int kk = 0; kk < BK; ++kk) {
      const float4 av = *(const float4*)&As[kk][ty * 4];
      const float4 bv = *(const float4*)&Bs[kk][tx * 4];
      const float a[4] = {av.x, av.y, av.z, av.w};
      const float b[4] = {bv.x, bv.y, bv.z, bv.w};
#pragma unroll
      for (int i = 0; i < 4; ++i)
#pragma unroll
        for (int j = 0; j < 4; ++j)
          acc[i][j] = fmaf(a[i], b[j], acc[i][j]);
    }
  }

#pragma unroll
  for (int i = 0; i < 4; ++i) {
    const int m = m0 + ty * 4 + i;
#pragma unroll
    for (int j = 0; j < 4; ++j) {
      const int n = n0 + tx * 4 + j;
      float v = acc[i][j];
      if (EPI == 0) {
        if (n < N) C[(size_t)m * ldc + n] = v;
      } else {
        v += bias[n];
        v = fmaxf(v, 0.f) + __logf(1.f + __expf(-fabsf(v)));
        if (n < N) C[(size_t)m * ldc + n] = v;
      }
    }
  }
}

// Depthwise causal conv1d (4 taps, left pad 3) + bias + silu.
__global__ __launch_bounds__(256) void conv_silu_k(
    const float* __restrict__ x, const float* __restrict__ cw,
    const float* __restrict__ cb, float* __restrict__ xc)
{
  const int id = (int)(blockIdx.x * 256 + threadIdx.x);
  const int dq = (id & 127) * 4;
  const int t  = id >> 7;
  const int l  = t & (kL - 1);

  float w[4][4];
#pragma unroll
  for (int j = 0; j < 4; ++j) {
    const float4 wt = *(const float4*)(cw + (size_t)(dq + j) * 4);
    w[j][0] = wt.x; w[j][1] = wt.y; w[j][2] = wt.z; w[j][3] = wt.w;
  }
  float r[4] = {cb[dq + 0], cb[dq + 1], cb[dq + 2], cb[dq + 3]};
#pragma unroll
  for (int k = 0; k < 4; ++k) {
    const int ll = l + k - 3;
    if (ll >= 0) {
      const float4 xv = *(const float4*)(x + (size_t)(t + k - 3) * kDInner + dq);
      r[0] = fmaf(xv.x, w[0][k], r[0]);
      r[1] = fmaf(xv.y, w[1][k], r[1]);
      r[2] = fmaf(xv.z, w[2][k], r[2]);
      r[3] = fmaf(xv.w, w[3][k], r[3]);
    }
  }
  *(float4*)(xc + (size_t)t * kDInner + dq) =
      make_float4(siluf(r[0]), siluf(r[1]), siluf(r[2]), siluf(r[3]));
}

// ---------------- Chunked selective scan (3 passes), lane = channel d ----------------
__global__ __launch_bounds__(256) void scan_part1(
    const float* __restrict__ delta, const float* __restrict__ xc,
    const float* __restrict__ dbc,  const float* __restrict__ A_log,
    float* __restrict__ Pbuf, float* __restrict__ hloc)
{
  const int tid = (int)(blockIdx.x * 256 + threadIdx.x);
  const int lane = tid & 63;
  const int gw = __builtin_amdgcn_readfirstlane(tid >> 6);
  const int dg = gw & 7;
  const int c  = (gw >> 3) & (kG - 1);
  const int b  = gw >> 7;
  const int d  = dg * 64 + lane;
  const int t0 = b * kL + c * kT;

  float A2[kDState], h[kDState];
#pragma unroll
  for (int n = 0; n < kDState; ++n) {
    A2[n] = -__expf(A_log[d * kDState + n]) * 1.44269504088896f;
    h[n] = 0.f;
  }
  const float* dp = delta + (size_t)t0 * kDInner + d;
  const float* xp = xc + (size_t)t0 * kDInner + d;
  float sd = 0.f;
#pragma unroll 2
  for (int l = 0; l < kT; ++l) {
    const float dl = dp[(size_t)l * kDInner];
    const float xv = xp[(size_t)l * kDInner];
    const float* bp = dbc + (size_t)(t0 + l) * kDbcW + kDtRank;  // uniform
    const float s = dl * xv;
    sd += dl;
#pragma unroll
    for (int n = 0; n < kDState; ++n) {
      const float dA = __builtin_amdgcn_exp2f(dl * A2[n]);
      h[n] = fmaf(dA, h[n], s * bp[n]);
    }
  }
  const size_t o0 = (size_t)((b * kG + c) * kDState) * kDInner + d;
#pragma unroll
  for (int n = 0; n < kDState; ++n) {
    Pbuf[o0 + (size_t)n * kDInner] = __builtin_amdgcn_exp2f(A2[n] * sd);
    hloc[o0 + (size_t)n * kDInner] = h[n];
  }
}

__global__ __launch_bounds__(256) void scan_part2(
    const float* __restrict__ Pbuf, const float* __restrict__ hloc,
    float* __restrict__ hin)
{
  const int t = (int)(blockIdx.x * 256 + threadIdx.x);
  const int d = t & (kDInner - 1);
  const int n = (t >> 9) & (kDState - 1);
  const int b = t >> 13;
  float carry = 0.f;
#pragma unroll
  for (int c = 0; c < kG; ++c) {
    const size_t idx = (size_t)((b * kG + c) * kDState + n) * kDInner + d;
    hin[idx] = carry;
    carry = fmaf(Pbuf[idx], carry, hloc[idx]);
  }
}

__global__ __launch_bounds__(256) void scan_part3(
    const float* __restrict__ delta, const float* __restrict__ xc,
    const float* __restrict__ dbc,  const float* __restrict__ z,
    const float* __restrict__ A_log, const float* __restrict__ D_skip,
    const float* __restrict__ hin,  float* __restrict__ y)
{
  const int tid = (int)(blockIdx.x * 256 + threadIdx.x);
  const int lane = tid & 63;
  const int gw = __builtin_amdgcn_readfirstlane(tid >> 6);
  const int dg = gw & 7;
  const int c  = (gw >> 3) & (kG - 1);
  const int b  = gw >> 7;
  const int d  = dg * 64 + lane;
  const int t0 = b * kL + c * kT;

  const size_t o0 = (size_t)((b * kG + c) * kDState) * kDInner + d;
  float A2[kDState], h[kDState];
#pragma unroll
  for (int n = 0; n < kDState; ++n) {
    A2[n] = -__expf(A_log[d * kDState + n]) * 1.44269504088896f;
    h[n] = hin[o0 + (size_t)n * kDInner];
  }
  const float Dv = D_skip[d];
  const float* dp = delta + (size_t)t0 * kDInner + d;
  const float* xp = xc + (size_t)t0 * kDInner + d;
  const float* zp = z + (size_t)t0 * kDInner + d;
  float* yp = y + (size_t)t0 * kDInner + d;
#pragma unroll 2
  for (int l = 0; l < kT; ++l) {
    const float dl = dp[(size_t)l * kDInner];
    const float xv = xp[(size_t)l * kDInner];
    const float zv = zp[(size_t)l * kDInner];
    const float* bp = dbc + (size_t)(t0 + l) * kDbcW + kDtRank;  // uniform
    const float s = dl * xv;
    float yv = 0.f;
#pragma unroll
    for (int n = 0; n < kDState; ++n) {
      const float dA = __builtin_amdgcn_exp2f(dl * A2[n]);
      h[n] = fmaf(dA, h[n], s * bp[n]);
      yv = fmaf(h[n], bp[kDState + n], yv);
    }
    yv = fmaf(xv, Dv, yv);
    yv *= zv / (1.f + __expf(-zv));
    yp[(size_t)l * kDInner] = yv;
  }
}

extern "C" void kernel_launch(void* const* d_in, const int* in_sizes, int n_in,
                              void* d_out, int out_size, void* d_ws, size_t ws_size,
                              hipStream_t stream) {
  (void)in_sizes; (void)n_in; (void)out_size; (void)ws_size;
  const float* token     = (const float*)d_in[0];
  const float* in_proj_w = (const float*)d_in[1];
  const float* conv_w    = (const float*)d_in[2];
  const float* conv_b    = (const float*)d_in[3];
  const float* x_proj_w  = (const float*)d_in[4];
  const float* dt_proj_w = (const float*)d_in[5];
  const float* dt_proj_b = (const float*)d_in[6];
  const float* A_log     = (const float*)d_in[7];
  const float* D_skip    = (const float*)d_in[8];
  const float* out_proj_w= (const float*)d_in[9];
  float* out = (float*)d_out;

  float* ws = (float*)d_ws;
  float* xbuf  = ws;                                    // kTok*512
  float* zbuf  = xbuf + (size_t)kTok * kDInner;         // kTok*512
  float* xcbuf = zbuf + (size_t)kTok * kDInner;         // kTok*512
  float* dbc   = xcbuf + (size_t)kTok * kDInner;        // kTok*48
  float* ybuf  = dbc + (size_t)kTok * kDbcW;            // kTok*512
  float* hin   = ybuf + (size_t)kTok * kDInner;         // B*G*N*D = 2M floats
  float* delta = xbuf;   // alias: x is dead after conv
  float* Pbuf  = ybuf;   // alias: die before y stores
  float* hloc  = ybuf + (size_t)kB * kG * kDState * kDInner;

  // K1: xz = token @ in_proj_w^T -> x, z   (bf16-split MFMA)
  {
    dim3 g(kTok / 128, (2 * kDInner) / 64);
    gemm_bt_mfma<1><<<g, 256, 0, stream>>>(token, kDModel, in_proj_w, kDModel,
                                           xbuf, kDInner, kDModel, zbuf);
  }
  // K2: depthwise conv + silu -> xc
  conv_silu_k<<<(kTok * (kDInner / 4)) / 256, 256, 0, stream>>>(xbuf, conv_w, conv_b, xcbuf);
  // K3: dbc = xc @ x_proj_w^T  (N=48, fp32)
  {
    dim3 g(kTok / 64, 1);
    gemm_bt_f32<0><<<g, 256, 0, stream>>>(xcbuf, kDInner, x_proj_w, kDInner,
                                          dbc, kDbcW, kDbcW, kDInner,
                                          nullptr, nullptr);
  }
  // K4: delta = softplus(dt @ dt_proj_w^T + b)   (K=16, fp32)
  {
    dim3 g(kTok / 64, kDInner / 64);
    gemm_bt_f32<2><<<g, 256, 0, stream>>>(dbc, kDbcW, dt_proj_w, kDtRank,
                                          delta, kDInner, kDInner, kDtRank,
                                          nullptr, dt_proj_b);
  }
  // S1/S2/S3: chunked selective scan (lane = channel)
  scan_part1<<<(kB * kG * 8) / 4, 256, 0, stream>>>(delta, xcbuf, dbc, A_log,
                                                    Pbuf, hloc);
  scan_part2<<<(kB * kDInner * kDState) / 256, 256, 0, stream>>>(Pbuf, hloc, hin);
  scan_part3<<<(kB * kG * 8) / 4, 256, 0, stream>>>(delta, xcbuf, dbc, zbuf,
                                                    A_log, D_skip, hin, ybuf);
  // K6: out = y @ out_proj_w^T   (bf16-split MFMA)
  {
    dim3 g(kTok / 128, kDModel / 64);
    gemm_bt_mfma<0><<<g, 256, 0, stream>>>(ybuf, kDInner, out_proj_w, kDInner,
                                           out, kDModel, kDInner, nullptr);
  }
}

// Round 9
// 299.436 us; speedup vs baseline: 3.5198x; 1.0064x over previous
//
#include <hip/hip_runtime.h>
#include <cstddef>

static constexpr int kDModel = 256;
static constexpr int kDInner = 512;
static constexpr int kDState = 16;
static constexpr int kDtRank = 16;
static constexpr int kB = 16;
static constexpr int kL = 1024;
static constexpr int kTok = kB * kL;   // 16384
static constexpr int kDbcW = kDtRank + 2 * kDState;  // 48
static constexpr int kT = 64;          // chunk length
static constexpr int kG = kL / kT;     // 16 chunks per sequence

typedef __attribute__((ext_vector_type(8))) short short8;
typedef __attribute__((ext_vector_type(4))) float f32x4;

__device__ __forceinline__ float siluf(float x) {
  return x / (1.0f + __expf(-x));
}

// Split two fp32 into packed bf16 hi (truncation) and bf16 lo (residual).
__device__ __forceinline__ void split2(float a, float b, unsigned& h, unsigned& l) {
  const unsigned ua = __float_as_uint(a), ub = __float_as_uint(b);
  const unsigned ha = ua & 0xffff0000u, hb = ub & 0xffff0000u;
  h = (ha >> 16) | hb;
  const float la = a - __uint_as_float(ha);
  const float lb = b - __uint_as_float(hb);
  l = (__float_as_uint(la) >> 16) | (__float_as_uint(lb) & 0xffff0000u);
}

// fp32[n] -> bf16 hi[n] + bf16 lo[n] (ushort arrays), vectorized x4.
__global__ __launch_bounds__(256) void split_k(
    const float* __restrict__ src, unsigned short* __restrict__ H,
    unsigned short* __restrict__ L, int n4)
{
  const int i = (int)(blockIdx.x * 256 + threadIdx.x);
  if (i >= n4) return;
  const float4 v = ((const float4*)src)[i];
  unsigned h0, l0, h1, l1;
  split2(v.x, v.y, h0, l0);
  split2(v.z, v.w, h1, l1);
  ((uint2*)H)[i] = make_uint2(h0, h1);
  ((uint2*)L)[i] = make_uint2(l0, l1);
}

// ---------------- pre-split bf16 MFMA GEMM:  C[m,n] = sum_k A[m,k]*B[n,k] ----------------
// A,B given as bf16 hi/lo ushort arrays (row-major, ld = K stride).
// Tile 128x64, BK=32, 4 waves (2x2), wave tile 64x32 = 4x2 frags of 16x16.
// Product: Ah*Bh + Ah*Bl + Al*Bh (~fp32 quality). NO split math in hot loop.
// EPI 0: C[m*ldc+n]. EPI 1: n<512 -> C (x), else -> out2 (z), both ld=512.
template <int EPI>
__global__ __launch_bounds__(256) void gemm_bt_mfma(
    const unsigned short* __restrict__ Ahg, const unsigned short* __restrict__ Alg, int lda,
    const unsigned short* __restrict__ Bhg, const unsigned short* __restrict__ Blg, int ldb,
    float* __restrict__ C, int ldc, int K,
    float* __restrict__ out2)
{
  __shared__ __align__(16) unsigned short Ah[128][40];  // K-dim padded 32->40
  __shared__ __align__(16) unsigned short Al[128][40];
  __shared__ __align__(16) unsigned short Bh[64][40];
  __shared__ __align__(16) unsigned short Bl[64][40];

  const int tid = (int)threadIdx.x;
  const int m0 = blockIdx.x * 128;
  const int n0 = blockIdx.y * 64;
  const int lane = tid & 63;
  const int w = tid >> 6, wm = w >> 1, wn = w & 1;
  const int fr = lane & 15;          // row (A) / col (B,D) within frag
  const int ko = (lane >> 4) * 8;    // k offset within BK=32

  const int ar = tid >> 1, ac = (tid & 1) * 16;   // A loader: 2 thr/row, 16 ushorts
  const int br = tid & 63, bc = (tid >> 6) * 8;   // B loader: 4 thr/row, 8 ushorts

  const unsigned short* ApH = Ahg + (size_t)(m0 + ar) * lda + ac;
  const unsigned short* ApL = Alg + (size_t)(m0 + ar) * lda + ac;
  const unsigned short* BpH = Bhg + (size_t)(n0 + br) * ldb + bc;
  const unsigned short* BpL = Blg + (size_t)(n0 + br) * ldb + bc;

  f32x4 acc[4][2];
#pragma unroll
  for (int i = 0; i < 4; ++i)
#pragma unroll
    for (int j = 0; j < 2; ++j) acc[i][j] = (f32x4){0.f, 0.f, 0.f, 0.f};

  for (int k0 = 0; k0 < K; k0 += 32) {
    const uint4 va0 = *(const uint4*)(ApH + k0);
    const uint4 va1 = *(const uint4*)(ApH + k0 + 8);
    const uint4 va2 = *(const uint4*)(ApL + k0);
    const uint4 va3 = *(const uint4*)(ApL + k0 + 8);
    const uint4 vb0 = *(const uint4*)(BpH + k0);
    const uint4 vb1 = *(const uint4*)(BpL + k0);
    __syncthreads();  // previous iter's frag reads done
    *(uint4*)&Ah[ar][ac] = va0; *(uint4*)&Ah[ar][ac + 8] = va1;
    *(uint4*)&Al[ar][ac] = va2; *(uint4*)&Al[ar][ac + 8] = va3;
    *(uint4*)&Bh[br][bc] = vb0; *(uint4*)&Bl[br][bc] = vb1;
    __syncthreads();

    short8 ah[4], al[4], bh[2], bl[2];
#pragma unroll
    for (int mi = 0; mi < 4; ++mi) {
      ah[mi] = *(const short8*)&Ah[wm * 64 + mi * 16 + fr][ko];
      al[mi] = *(const short8*)&Al[wm * 64 + mi * 16 + fr][ko];
    }
#pragma unroll
    for (int ni = 0; ni < 2; ++ni) {
      bh[ni] = *(const short8*)&Bh[wn * 32 + ni * 16 + fr][ko];
      bl[ni] = *(const short8*)&Bl[wn * 32 + ni * 16 + fr][ko];
    }
#pragma unroll
    for (int mi = 0; mi < 4; ++mi)
#pragma unroll
      for (int ni = 0; ni < 2; ++ni) {
        acc[mi][ni] = __builtin_amdgcn_mfma_f32_16x16x32_bf16(ah[mi], bh[ni], acc[mi][ni], 0, 0, 0);
        acc[mi][ni] = __builtin_amdgcn_mfma_f32_16x16x32_bf16(ah[mi], bl[ni], acc[mi][ni], 0, 0, 0);
        acc[mi][ni] = __builtin_amdgcn_mfma_f32_16x16x32_bf16(al[mi], bh[ni], acc[mi][ni], 0, 0, 0);
      }
  }

  float* Cb;
  int nbase, ldout;
  if (EPI == 1) {
    Cb = (n0 < kDInner) ? C : out2;
    nbase = (n0 & (kDInner - 1)) + wn * 32 + fr;
    ldout = kDInner;
  } else {
    Cb = C;
    nbase = n0 + wn * 32 + fr;
    ldout = ldc;
  }
#pragma unroll
  for (int mi = 0; mi < 4; ++mi) {
    const int mrow = m0 + wm * 64 + mi * 16 + (lane >> 4) * 4;
#pragma unroll
    for (int ni = 0; ni < 2; ++ni)
#pragma unroll
      for (int r = 0; r < 4; ++r)
        Cb[(size_t)(mrow + r) * ldout + nbase + ni * 16] = acc[mi][ni][r];
  }
}

// C[m,n] = sum_k A[m*lda+k] * B[n*ldb+k]  (fp32 VALU path for small GEMMs)
// EPI 0: plain store. EPI 2: softplus(acc + bias[n]).
template <int EPI>
__global__ __launch_bounds__(256) void gemm_bt_f32(
    const float* __restrict__ A, int lda,
    const float* __restrict__ B, int ldb,
    float* __restrict__ C, int ldc,
    int N, int K,
    float* __restrict__ out2,
    const float* __restrict__ bias)
{
  constexpr int BM = 64, BN = 64, BK = 16;
  __shared__ float As[BK][BM];
  __shared__ float Bs[BK][BN];
  const int m0 = blockIdx.x * BM;
  const int n0 = blockIdx.y * BN;
  const int tid = (int)threadIdx.x;
  const int tx = tid & 15;
  const int ty = tid >> 4;
  const int lr = tid >> 2;
  const int lk = (tid & 3) * 4;

  float acc[4][4] = {};

  for (int k0 = 0; k0 < K; k0 += BK) {
    const float4 a4 = *(const float4*)(A + (size_t)(m0 + lr) * lda + k0 + lk);
    float4 b4 = make_float4(0.f, 0.f, 0.f, 0.f);
    if (n0 + lr < N)
      b4 = *(const float4*)(B + (size_t)(n0 + lr) * ldb + k0 + lk);
    __syncthreads();
    As[lk + 0][lr] = a4.x; As[lk + 1][lr] = a4.y;
    As[lk + 2][lr] = a4.z; As[lk + 3][lr] = a4.w;
    Bs[lk + 0][lr] = b4.x; Bs[lk + 1][lr] = b4.y;
    Bs[lk + 2][lr] = b4.z; Bs[lk + 3][lr] = b4.w;
    __syncthreads();
#pragma unroll
    for (int kk = 0; kk < BK; ++kk) {
      const float4 av = *(const float4*)&As[kk][ty * 4];
      const float4 bv = *(const float4*)&Bs[kk][tx * 4];
      const float a[4] = {av.x, av.y, av.z, av.w};
      const float b[4] = {bv.x, bv.y, bv.z, bv.w};
#pragma unroll
      for (int i = 0; i < 4; ++i)
#pragma unroll
        for (int j = 0; j < 4; ++j)
          acc[i][j] = fmaf(a[i], b[j], acc[i][j]);
    }
  }

#pragma unroll
  for (int i = 0; i < 4; ++i) {
    const int m = m0 + ty * 4 + i;
#pragma unroll
    for (int j = 0; j < 4; ++j) {
      const int n = n0 + tx * 4 + j;
      float v = acc[i][j];
      if (EPI == 0) {
        if (n < N) C[(size_t)m * ldc + n] = v;
      } else {
        v += bias[n];
        v = fmaxf(v, 0.f) + __logf(1.f + __expf(-fabsf(v)));
        if (n < N) C[(size_t)m * ldc + n] = v;
      }
    }
  }
}

// Depthwise causal conv1d (4 taps, left pad 3) + bias + silu.
__global__ __launch_bounds__(256) void conv_silu_k(
    const float* __restrict__ x, const float* __restrict__ cw,
    const float* __restrict__ cb, float* __restrict__ xc)
{
  const int id = (int)(blockIdx.x * 256 + threadIdx.x);
  const int dq = (id & 127) * 4;
  const int t  = id >> 7;
  const int l  = t & (kL - 1);

  float w[4][4];
#pragma unroll
  for (int j = 0; j < 4; ++j) {
    const float4 wt = *(const float4*)(cw + (size_t)(dq + j) * 4);
    w[j][0] = wt.x; w[j][1] = wt.y; w[j][2] = wt.z; w[j][3] = wt.w;
  }
  float r[4] = {cb[dq + 0], cb[dq + 1], cb[dq + 2], cb[dq + 3]};
#pragma unroll
  for (int k = 0; k < 4; ++k) {
    const int ll = l + k - 3;
    if (ll >= 0) {
      const float4 xv = *(const float4*)(x + (size_t)(t + k - 3) * kDInner + dq);
      r[0] = fmaf(xv.x, w[0][k], r[0]);
      r[1] = fmaf(xv.y, w[1][k], r[1]);
      r[2] = fmaf(xv.z, w[2][k], r[2]);
      r[3] = fmaf(xv.w, w[3][k], r[3]);
    }
  }
  *(float4*)(xc + (size_t)t * kDInner + dq) =
      make_float4(siluf(r[0]), siluf(r[1]), siluf(r[2]), siluf(r[3]));
}

// ---------------- Chunked selective scan (3 passes), lane = channel d ----------------
__global__ __launch_bounds__(256) void scan_part1(
    const float* __restrict__ delta, const float* __restrict__ xc,
    const float* __restrict__ dbc,  const float* __restrict__ A_log,
    float* __restrict__ Pbuf, float* __restrict__ hloc)
{
  const int tid = (int)(blockIdx.x * 256 + threadIdx.x);
  const int lane = tid & 63;
  const int gw = __builtin_amdgcn_readfirstlane(tid >> 6);
  const int dg = gw & 7;
  const int c  = (gw >> 3) & (kG - 1);
  const int b  = gw >> 7;
  const int d  = dg * 64 + lane;
  const int t0 = b * kL + c * kT;

  float A2[kDState], h[kDState];
#pragma unroll
  for (int n = 0; n < kDState; ++n) {
    A2[n] = -__expf(A_log[d * kDState + n]) * 1.44269504088896f;
    h[n] = 0.f;
  }
  const float* dp = delta + (size_t)t0 * kDInner + d;
  const float* xp = xc + (size_t)t0 * kDInner + d;
  float sd = 0.f;
#pragma unroll 2
  for (int l = 0; l < kT; ++l) {
    const float dl = dp[(size_t)l * kDInner];
    const float xv = xp[(size_t)l * kDInner];
    const float* bp = dbc + (size_t)(t0 + l) * kDbcW + kDtRank;  // uniform
    const float s = dl * xv;
    sd += dl;
#pragma unroll
    for (int n = 0; n < kDState; ++n) {
      const float dA = __builtin_amdgcn_exp2f(dl * A2[n]);
      h[n] = fmaf(dA, h[n], s * bp[n]);
    }
  }
  const size_t o0 = (size_t)((b * kG + c) * kDState) * kDInner + d;
#pragma unroll
  for (int n = 0; n < kDState; ++n) {
    Pbuf[o0 + (size_t)n * kDInner] = __builtin_amdgcn_exp2f(A2[n] * sd);
    hloc[o0 + (size_t)n * kDInner] = h[n];
  }
}

__global__ __launch_bounds__(256) void scan_part2(
    const float* __restrict__ Pbuf, const float* __restrict__ hloc,
    float* __restrict__ hin)
{
  const int t = (int)(blockIdx.x * 256 + threadIdx.x);
  const int d = t & (kDInner - 1);
  const int n = (t >> 9) & (kDState - 1);
  const int b = t >> 13;
  float carry = 0.f;
#pragma unroll
  for (int c = 0; c < kG; ++c) {
    const size_t idx = (size_t)((b * kG + c) * kDState + n) * kDInner + d;
    hin[idx] = carry;
    carry = fmaf(Pbuf[idx], carry, hloc[idx]);
  }
}

// S3: local scan from h_in; y = <h,C> + x*D, gated by silu(z).
// Emits y as bf16 hi/lo pair (feeds out_proj MFMA without a split pass).
__global__ __launch_bounds__(256) void scan_part3(
    const float* __restrict__ delta, const float* __restrict__ xc,
    const float* __restrict__ dbc,  const float* __restrict__ z,
    const float* __restrict__ A_log, const float* __restrict__ D_skip,
    const float* __restrict__ hin,
    unsigned short* __restrict__ yh, unsigned short* __restrict__ yl)
{
  const int tid = (int)(blockIdx.x * 256 + threadIdx.x);
  const int lane = tid & 63;
  const int gw = __builtin_amdgcn_readfirstlane(tid >> 6);
  const int dg = gw & 7;
  const int c  = (gw >> 3) & (kG - 1);
  const int b  = gw >> 7;
  const int d  = dg * 64 + lane;
  const int t0 = b * kL + c * kT;

  const size_t o0 = (size_t)((b * kG + c) * kDState) * kDInner + d;
  float A2[kDState], h[kDState];
#pragma unroll
  for (int n = 0; n < kDState; ++n) {
    A2[n] = -__expf(A_log[d * kDState + n]) * 1.44269504088896f;
    h[n] = hin[o0 + (size_t)n * kDInner];
  }
  const float Dv = D_skip[d];
  const float* dp = delta + (size_t)t0 * kDInner + d;
  const float* xp = xc + (size_t)t0 * kDInner + d;
  const float* zp = z + (size_t)t0 * kDInner + d;
  unsigned short* yhp = yh + (size_t)t0 * kDInner + d;
  unsigned short* ylp = yl + (size_t)t0 * kDInner + d;
#pragma unroll 2
  for (int l = 0; l < kT; ++l) {
    const float dl = dp[(size_t)l * kDInner];
    const float xv = xp[(size_t)l * kDInner];
    const float zv = zp[(size_t)l * kDInner];
    const float* bp = dbc + (size_t)(t0 + l) * kDbcW + kDtRank;  // uniform
    const float s = dl * xv;
    float yv = 0.f;
#pragma unroll
    for (int n = 0; n < kDState; ++n) {
      const float dA = __builtin_amdgcn_exp2f(dl * A2[n]);
      h[n] = fmaf(dA, h[n], s * bp[n]);
      yv = fmaf(h[n], bp[kDState + n], yv);
    }
    yv = fmaf(xv, Dv, yv);
    yv *= zv / (1.f + __expf(-zv));
    const unsigned u = __float_as_uint(yv);
    const unsigned hi = u & 0xffff0000u;
    yhp[(size_t)l * kDInner] = (unsigned short)(u >> 16);
    ylp[(size_t)l * kDInner] =
        (unsigned short)(__float_as_uint(yv - __uint_as_float(hi)) >> 16);
  }
}

extern "C" void kernel_launch(void* const* d_in, const int* in_sizes, int n_in,
                              void* d_out, int out_size, void* d_ws, size_t ws_size,
                              hipStream_t stream) {
  (void)in_sizes; (void)n_in; (void)out_size; (void)ws_size;
  const float* token     = (const float*)d_in[0];
  const float* in_proj_w = (const float*)d_in[1];
  const float* conv_w    = (const float*)d_in[2];
  const float* conv_b    = (const float*)d_in[3];
  const float* x_proj_w  = (const float*)d_in[4];
  const float* dt_proj_w = (const float*)d_in[5];
  const float* dt_proj_b = (const float*)d_in[6];
  const float* A_log     = (const float*)d_in[7];
  const float* D_skip    = (const float*)d_in[8];
  const float* out_proj_w= (const float*)d_in[9];
  float* out = (float*)d_out;

  float* ws = (float*)d_ws;
  float* xbuf  = ws;                                    // kTok*512 (x, then delta)
  float* zbuf  = xbuf + (size_t)kTok * kDInner;         // kTok*512
  float* xcbuf = zbuf + (size_t)kTok * kDInner;         // kTok*512
  float* dbc   = xcbuf + (size_t)kTok * kDInner;        // kTok*48
  float* ybuf  = dbc + (size_t)kTok * kDbcW;            // kTok*512 multi-use region
  float* hin   = ybuf + (size_t)kTok * kDInner;         // 2M floats
  float* delta = xbuf;

  // ybuf region timeline: [tokH|tokL] during K1  ->  [Pbuf|hloc] S1-S2  ->  [yh|yl] S3-K6
  unsigned short* tokH = (unsigned short*)ybuf;                 // kTok*256 ushorts
  unsigned short* tokL = tokH + (size_t)kTok * kDModel;
  float* Pbuf = ybuf;                                           // 2M floats
  float* hloc = ybuf + (size_t)kB * kG * kDState * kDInner;     // 2M floats
  unsigned short* yh = (unsigned short*)ybuf;                   // kTok*512 ushorts
  unsigned short* yl = yh + (size_t)kTok * kDInner;
  // hin region holds ipH/ipL during K1 (dead before S2 writes hin)
  unsigned short* ipH = (unsigned short*)hin;                   // 1024*256 ushorts
  unsigned short* ipL = ipH + (size_t)2 * kDInner * kDModel;
  // op splits live after hin permanently (+0.5 MB)
  unsigned short* opH = (unsigned short*)(hin + (size_t)kB * kDInner * kG * kDState);
  unsigned short* opL = opH + (size_t)kDModel * kDInner;

  // S0: pre-split fp32 -> bf16 hi/lo (same total bytes as fp32)
  split_k<<<(kTok * kDModel / 4) / 256, 256, 0, stream>>>(token, tokH, tokL,
                                                          kTok * kDModel / 4);
  split_k<<<(2 * kDInner * kDModel / 4) / 256, 256, 0, stream>>>(
      in_proj_w, ipH, ipL, 2 * kDInner * kDModel / 4);
  split_k<<<(kDModel * kDInner / 4) / 256, 256, 0, stream>>>(
      out_proj_w, opH, opL, kDModel * kDInner / 4);

  // K1: xz = token @ in_proj_w^T -> x, z   (pre-split MFMA)
  {
    dim3 g(kTok / 128, (2 * kDInner) / 64);
    gemm_bt_mfma<1><<<g, 256, 0, stream>>>(tokH, tokL, kDModel, ipH, ipL, kDModel,
                                           xbuf, kDInner, kDModel, zbuf);
  }
  // K2: depthwise conv + silu -> xc
  conv_silu_k<<<(kTok * (kDInner / 4)) / 256, 256, 0, stream>>>(xbuf, conv_w, conv_b, xcbuf);
  // K3: dbc = xc @ x_proj_w^T  (N=48, fp32)
  {
    dim3 g(kTok / 64, 1);
    gemm_bt_f32<0><<<g, 256, 0, stream>>>(xcbuf, kDInner, x_proj_w, kDInner,
                                          dbc, kDbcW, kDbcW, kDInner,
                                          nullptr, nullptr);
  }
  // K4: delta = softplus(dt @ dt_proj_w^T + b)   (K=16, fp32)
  {
    dim3 g(kTok / 64, kDInner / 64);
    gemm_bt_f32<2><<<g, 256, 0, stream>>>(dbc, kDbcW, dt_proj_w, kDtRank,
                                          delta, kDInner, kDInner, kDtRank,
                                          nullptr, dt_proj_b);
  }
  // S1/S2/S3: chunked selective scan (lane = channel); S3 emits y as bf16 hi/lo
  scan_part1<<<(kB * kG * 8) / 4, 256, 0, stream>>>(delta, xcbuf, dbc, A_log,
                                                    Pbuf, hloc);
  scan_part2<<<(kB * kDInner * kDState) / 256, 256, 0, stream>>>(Pbuf, hloc, hin);
  scan_part3<<<(kB * kG * 8) / 4, 256, 0, stream>>>(delta, xcbuf, dbc, zbuf,
                                                    A_log, D_skip, hin, yh, yl);
  // K6: out = y @ out_proj_w^T   (pre-split MFMA)
  {
    dim3 g(kTok / 128, kDModel / 64);
    gemm_bt_mfma<0><<<g, 256, 0, stream>>>(yh, yl, kDInner, opH, opL, kDInner,
                                           out, kDModel, kDInner, nullptr);
  }
}

// Round 10
// 282.439 us; speedup vs baseline: 3.7316x; 1.0602x over previous
//
#include <hip/hip_runtime.h>
#include <cstddef>

static constexpr int kDModel = 256;
static constexpr int kDInner = 512;
static constexpr int kDState = 16;
static constexpr int kDtRank = 16;
static constexpr int kB = 16;
static constexpr int kL = 1024;
static constexpr int kTok = kB * kL;   // 16384
static constexpr int kDbcW = kDtRank + 2 * kDState;  // 48
static constexpr int kT = 64;          // chunk length
static constexpr int kG = kL / kT;     // 16 chunks per sequence

typedef __attribute__((ext_vector_type(8))) short short8;
typedef __attribute__((ext_vector_type(4))) float f32x4;

__device__ __forceinline__ float siluf(float x) {
  return x / (1.0f + __expf(-x));
}

// Split two fp32 into packed bf16 hi (truncation) and bf16 lo (residual).
__device__ __forceinline__ void split2(float a, float b, unsigned& h, unsigned& l) {
  const unsigned ua = __float_as_uint(a), ub = __float_as_uint(b);
  const unsigned ha = ua & 0xffff0000u, hb = ub & 0xffff0000u;
  h = (ha >> 16) | hb;
  const float la = a - __uint_as_float(ha);
  const float lb = b - __uint_as_float(hb);
  l = (__float_as_uint(la) >> 16) | (__float_as_uint(lb) & 0xffff0000u);
}

// fp32[n] -> bf16 hi[n] + bf16 lo[n] (ushort arrays), vectorized x4.
__global__ __launch_bounds__(256) void split_k(
    const float* __restrict__ src, unsigned short* __restrict__ H,
    unsigned short* __restrict__ L, int n4)
{
  const int i = (int)(blockIdx.x * 256 + threadIdx.x);
  if (i >= n4) return;
  const float4 v = ((const float4*)src)[i];
  unsigned h0, l0, h1, l1;
  split2(v.x, v.y, h0, l0);
  split2(v.z, v.w, h1, l1);
  ((uint2*)H)[i] = make_uint2(h0, h1);
  ((uint2*)L)[i] = make_uint2(l0, l1);
}

// Direct global->LDS 16B async copy. LDS dest = wave-uniform base + lane*16.
__device__ __forceinline__ void gload16(const unsigned short* g, unsigned short* l) {
  __builtin_amdgcn_global_load_lds(
      (const __attribute__((address_space(1))) unsigned int*)g,
      (__attribute__((address_space(3))) unsigned int*)l, 16, 0, 0);
}

// ---------------- pre-split bf16 MFMA GEMM (m97 structure) ----------------
// C[m,n] = sum_k A[m,k]*B[n,k]; A,B as bf16 hi/lo ushort arrays (ld = K stride).
// Tile 128x64, BK=32, 4 waves (2x2), wave tile 64x32, mfma_f32_16x16x32_bf16,
// product Ah*Bh + Ah*Bl + Al*Bh. Staging via global_load_lds (no ds_write, no
// staging VALU). LDS linear [row][32 ushorts]; k-slot XOR swizzle
// (slot ^= (row>>1)&3) applied on the GLOBAL source address (m173 pattern) and
// on the frag ds_read -> max 2-way bank aliasing (free).
// EPI 0: C[m*ldc+n]. EPI 1: n<512 -> C (x), else -> out2 (z), both ld=512.
template <int EPI>
__global__ __launch_bounds__(256) void gemm_bt_mfma(
    const unsigned short* __restrict__ Ahg, const unsigned short* __restrict__ Alg, int lda,
    const unsigned short* __restrict__ Bhg, const unsigned short* __restrict__ Blg, int ldb,
    float* __restrict__ C, int ldc, int K,
    float* __restrict__ out2)
{
  __shared__ __align__(16) unsigned short lds[12288];  // 24 KB
  unsigned short* Ah = lds;           // 128x32
  unsigned short* Al = lds + 4096;    // 128x32
  unsigned short* Bh = lds + 8192;    // 64x32
  unsigned short* Bl = lds + 10240;   // 64x32

  const int tid = (int)threadIdx.x;
  const int m0 = blockIdx.x * 128;
  const int n0 = blockIdx.y * 64;
  const int lane = tid & 63;
  const int w = tid >> 6, wm = w >> 1, wn = w & 1;
  const int fr = lane & 15;          // row within frag
  const int j = lane >> 4;           // k-slot index (8 ushorts each)

  // stage mapping: 1KB chunk = 16 rows x 64B; lane -> row r0+(lane>>2), slot lane&3
  const int srow = lane >> 2;
  const int sslot = lane & 3;

  f32x4 acc[4][2];
#pragma unroll
  for (int i = 0; i < 4; ++i)
#pragma unroll
    for (int jj = 0; jj < 2; ++jj) acc[i][jj] = (f32x4){0.f, 0.f, 0.f, 0.f};

  const int r1 = 16 * w + srow;        // chunk w rows   (A + B)
  const int r2 = r1 + 64;              // chunk w+4 rows (A only)
  const int s1 = (sslot ^ ((r1 >> 1) & 3)) * 8;  // swizzled k-offset (ushorts)
  const int s2 = (sslot ^ ((r2 >> 1) & 3)) * 8;
  const unsigned short* A1h = Ahg + (size_t)(m0 + r1) * lda + s1;
  const unsigned short* A2h = Ahg + (size_t)(m0 + r2) * lda + s2;
  const unsigned short* A1l = Alg + (size_t)(m0 + r1) * lda + s1;
  const unsigned short* A2l = Alg + (size_t)(m0 + r2) * lda + s2;
  const unsigned short* B1h = Bhg + (size_t)(n0 + r1) * ldb + s1;
  const unsigned short* B1l = Blg + (size_t)(n0 + r1) * ldb + s1;
  unsigned short* dA1 = Ah + 512 * w;        // wave-uniform LDS chunk bases
  unsigned short* dA2 = Ah + 512 * (w + 4);
  unsigned short* dL1 = Al + 512 * w;
  unsigned short* dL2 = Al + 512 * (w + 4);
  unsigned short* dB1 = Bh + 512 * w;
  unsigned short* dB2 = Bl + 512 * w;

  for (int k0 = 0; k0 < K; k0 += 32) {
    __syncthreads();                   // prev iter's frag reads done
    gload16(A1h + k0, dA1);
    gload16(A2h + k0, dA2);
    gload16(A1l + k0, dL1);
    gload16(A2l + k0, dL2);
    gload16(B1h + k0, dB1);
    gload16(B1l + k0, dB2);
    __syncthreads();                   // drains vmcnt -> LDS tile valid

    short8 ah[4], al[4], bh[2], bl[2];
#pragma unroll
    for (int mi = 0; mi < 4; ++mi) {
      const int R = wm * 64 + mi * 16 + fr;
      const int off = R * 32 + ((j ^ ((R >> 1) & 3)) * 8);
      ah[mi] = *(const short8*)&Ah[off];
      al[mi] = *(const short8*)&Al[off];
    }
#pragma unroll
    for (int ni = 0; ni < 2; ++ni) {
      const int R = wn * 32 + ni * 16 + fr;
      const int off = R * 32 + ((j ^ ((R >> 1) & 3)) * 8);
      bh[ni] = *(const short8*)&Bh[off];
      bl[ni] = *(const short8*)&Bl[off];
    }
#pragma unroll
    for (int mi = 0; mi < 4; ++mi)
#pragma unroll
      for (int ni = 0; ni < 2; ++ni) {
        acc[mi][ni] = __builtin_amdgcn_mfma_f32_16x16x32_bf16(ah[mi], bh[ni], acc[mi][ni], 0, 0, 0);
        acc[mi][ni] = __builtin_amdgcn_mfma_f32_16x16x32_bf16(ah[mi], bl[ni], acc[mi][ni], 0, 0, 0);
        acc[mi][ni] = __builtin_amdgcn_mfma_f32_16x16x32_bf16(al[mi], bh[ni], acc[mi][ni], 0, 0, 0);
      }
  }

  float* Cb;
  int nbase, ldout;
  if (EPI == 1) {
    Cb = (n0 < kDInner) ? C : out2;
    nbase = (n0 & (kDInner - 1)) + wn * 32 + fr;
    ldout = kDInner;
  } else {
    Cb = C;
    nbase = n0 + wn * 32 + fr;
    ldout = ldc;
  }
#pragma unroll
  for (int mi = 0; mi < 4; ++mi) {
    const int mrow = m0 + wm * 64 + mi * 16 + (lane >> 4) * 4;
#pragma unroll
    for (int ni = 0; ni < 2; ++ni)
#pragma unroll
      for (int r = 0; r < 4; ++r)
        Cb[(size_t)(mrow + r) * ldout + nbase + ni * 16] = acc[mi][ni][r];
  }
}

// C[m,n] = sum_k A[m*lda+k] * B[n*ldb+k]  (fp32 VALU path for small GEMMs)
// EPI 0: plain store. EPI 2: softplus(acc + bias[n]).
template <int EPI>
__global__ __launch_bounds__(256) void gemm_bt_f32(
    const float* __restrict__ A, int lda,
    const float* __restrict__ B, int ldb,
    float* __restrict__ C, int ldc,
    int N, int K,
    float* __restrict__ out2,
    const float* __restrict__ bias)
{
  constexpr int BM = 64, BN = 64, BK = 16;
  __shared__ float As[BK][BM];
  __shared__ float Bs[BK][BN];
  const int m0 = blockIdx.x * BM;
  const int n0 = blockIdx.y * BN;
  const int tid = (int)threadIdx.x;
  const int tx = tid & 15;
  const int ty = tid >> 4;
  const int lr = tid >> 2;
  const int lk = (tid & 3) * 4;

  float acc[4][4] = {};

  for (int k0 = 0; k0 < K; k0 += BK) {
    const float4 a4 = *(const float4*)(A + (size_t)(m0 + lr) * lda + k0 + lk);
    float4 b4 = make_float4(0.f, 0.f, 0.f, 0.f);
    if (n0 + lr < N)
      b4 = *(const float4*)(B + (size_t)(n0 + lr) * ldb + k0 + lk);
    __syncthreads();
    As[lk + 0][lr] = a4.x; As[lk + 1][lr] = a4.y;
    As[lk + 2][lr] = a4.z; As[lk + 3][lr] = a4.w;
    Bs[lk + 0][lr] = b4.x; Bs[lk + 1][lr] = b4.y;
    Bs[lk + 2][lr] = b4.z; Bs[lk + 3][lr] = b4.w;
    __syncthreads();
#pragma unroll
    for (int kk = 0; kk < BK; ++kk) {
      const float4 av = *(const float4*)&As[kk][ty * 4];
      const float4 bv = *(const float4*)&Bs[kk][tx * 4];
      const float a[4] = {av.x, av.y, av.z, av.w};
      const float b[4] = {bv.x, bv.y, bv.z, bv.w};
#pragma unroll
      for (int i = 0; i < 4; ++i)
#pragma unroll
        for (int j = 0; j < 4; ++j)
          acc[i][j] = fmaf(a[i], b[j], acc[i][j]);
    }
  }

#pragma unroll
  for (int i = 0; i < 4; ++i) {
    const int m = m0 + ty * 4 + i;
#pragma unroll
    for (int j = 0; j < 4; ++j) {
      const int n = n0 + tx * 4 + j;
      float v = acc[i][j];
      if (EPI == 0) {
        if (n < N) C[(size_t)m * ldc + n] = v;
      } else {
        v += bias[n];
        v = fmaxf(v, 0.f) + __logf(1.f + __expf(-fabsf(v)));
        if (n < N) C[(size_t)m * ldc + n] = v;
      }
    }
  }
}

// Depthwise causal conv1d (4 taps, left pad 3) + bias + silu.
__global__ __launch_bounds__(256) void conv_silu_k(
    const float* __restrict__ x, const float* __restrict__ cw,
    const float* __restrict__ cb, float* __restrict__ xc)
{
  const int id = (int)(blockIdx.x * 256 + threadIdx.x);
  const int dq = (id & 127) * 4;
  const int t  = id >> 7;
  const int l  = t & (kL - 1);

  float w[4][4];
#pragma unroll
  for (int j = 0; j < 4; ++j) {
    const float4 wt = *(const float4*)(cw + (size_t)(dq + j) * 4);
    w[j][0] = wt.x; w[j][1] = wt.y; w[j][2] = wt.z; w[j][3] = wt.w;
  }
  float r[4] = {cb[dq + 0], cb[dq + 1], cb[dq + 2], cb[dq + 3]};
#pragma unroll
  for (int k = 0; k < 4; ++k) {
    const int ll = l + k - 3;
    if (ll >= 0) {
      const float4 xv = *(const float4*)(x + (size_t)(t + k - 3) * kDInner + dq);
      r[0] = fmaf(xv.x, w[0][k], r[0]);
      r[1] = fmaf(xv.y, w[1][k], r[1]);
      r[2] = fmaf(xv.z, w[2][k], r[2]);
      r[3] = fmaf(xv.w, w[3][k], r[3]);
    }
  }
  *(float4*)(xc + (size_t)t * kDInner + dq) =
      make_float4(siluf(r[0]), siluf(r[1]), siluf(r[2]), siluf(r[3]));
}

// ---------------- Chunked selective scan (3 passes), lane = channel d ----------------
__global__ __launch_bounds__(256) void scan_part1(
    const float* __restrict__ delta, const float* __restrict__ xc,
    const float* __restrict__ dbc,  const float* __restrict__ A_log,
    float* __restrict__ Pbuf, float* __restrict__ hloc)
{
  const int tid = (int)(blockIdx.x * 256 + threadIdx.x);
  const int lane = tid & 63;
  const int gw = __builtin_amdgcn_readfirstlane(tid >> 6);
  const int dg = gw & 7;
  const int c  = (gw >> 3) & (kG - 1);
  const int b  = gw >> 7;
  const int d  = dg * 64 + lane;
  const int t0 = b * kL + c * kT;

  float A2[kDState], h[kDState];
#pragma unroll
  for (int n = 0; n < kDState; ++n) {
    A2[n] = -__expf(A_log[d * kDState + n]) * 1.44269504088896f;
    h[n] = 0.f;
  }
  const float* dp = delta + (size_t)t0 * kDInner + d;
  const float* xp = xc + (size_t)t0 * kDInner + d;
  float sd = 0.f;
#pragma unroll 2
  for (int l = 0; l < kT; ++l) {
    const float dl = dp[(size_t)l * kDInner];
    const float xv = xp[(size_t)l * kDInner];
    const float* bp = dbc + (size_t)(t0 + l) * kDbcW + kDtRank;  // uniform
    const float s = dl * xv;
    sd += dl;
#pragma unroll
    for (int n = 0; n < kDState; ++n) {
      const float dA = __builtin_amdgcn_exp2f(dl * A2[n]);
      h[n] = fmaf(dA, h[n], s * bp[n]);
    }
  }
  const size_t o0 = (size_t)((b * kG + c) * kDState) * kDInner + d;
#pragma unroll
  for (int n = 0; n < kDState; ++n) {
    Pbuf[o0 + (size_t)n * kDInner] = __builtin_amdgcn_exp2f(A2[n] * sd);
    hloc[o0 + (size_t)n * kDInner] = h[n];
  }
}

__global__ __launch_bounds__(256) void scan_part2(
    const float* __restrict__ Pbuf, const float* __restrict__ hloc,
    float* __restrict__ hin)
{
  const int t = (int)(blockIdx.x * 256 + threadIdx.x);
  const int d = t & (kDInner - 1);
  const int n = (t >> 9) & (kDState - 1);
  const int b = t >> 13;
  float carry = 0.f;
#pragma unroll
  for (int c = 0; c < kG; ++c) {
    const size_t idx = (size_t)((b * kG + c) * kDState + n) * kDInner + d;
    hin[idx] = carry;
    carry = fmaf(Pbuf[idx], carry, hloc[idx]);
  }
}

// S3: local scan from h_in; y = <h,C> + x*D, gated by silu(z).
// Emits y as bf16 hi/lo pair (feeds out_proj MFMA without a split pass).
__global__ __launch_bounds__(256) void scan_part3(
    const float* __restrict__ delta, const float* __restrict__ xc,
    const float* __restrict__ dbc,  const float* __restrict__ z,
    const float* __restrict__ A_log, const float* __restrict__ D_skip,
    const float* __restrict__ hin,
    unsigned short* __restrict__ yh, unsigned short* __restrict__ yl)
{
  const int tid = (int)(blockIdx.x * 256 + threadIdx.x);
  const int lane = tid & 63;
  const int gw = __builtin_amdgcn_readfirstlane(tid >> 6);
  const int dg = gw & 7;
  const int c  = (gw >> 3) & (kG - 1);
  const int b  = gw >> 7;
  const int d  = dg * 64 + lane;
  const int t0 = b * kL + c * kT;

  const size_t o0 = (size_t)((b * kG + c) * kDState) * kDInner + d;
  float A2[kDState], h[kDState];
#pragma unroll
  for (int n = 0; n < kDState; ++n) {
    A2[n] = -__expf(A_log[d * kDState + n]) * 1.44269504088896f;
    h[n] = hin[o0 + (size_t)n * kDInner];
  }
  const float Dv = D_skip[d];
  const float* dp = delta + (size_t)t0 * kDInner + d;
  const float* xp = xc + (size_t)t0 * kDInner + d;
  const float* zp = z + (size_t)t0 * kDInner + d;
  unsigned short* yhp = yh + (size_t)t0 * kDInner + d;
  unsigned short* ylp = yl + (size_t)t0 * kDInner + d;
#pragma unroll 2
  for (int l = 0; l < kT; ++l) {
    const float dl = dp[(size_t)l * kDInner];
    const float xv = xp[(size_t)l * kDInner];
    const float zv = zp[(size_t)l * kDInner];
    const float* bp = dbc + (size_t)(t0 + l) * kDbcW + kDtRank;  // uniform
    const float s = dl * xv;
    float yv = 0.f;
#pragma unroll
    for (int n = 0; n < kDState; ++n) {
      const float dA = __builtin_amdgcn_exp2f(dl * A2[n]);
      h[n] = fmaf(dA, h[n], s * bp[n]);
      yv = fmaf(h[n], bp[kDState + n], yv);
    }
    yv = fmaf(xv, Dv, yv);
    yv *= zv / (1.f + __expf(-zv));
    const unsigned u = __float_as_uint(yv);
    const unsigned hi = u & 0xffff0000u;
    yhp[(size_t)l * kDInner] = (unsigned short)(u >> 16);
    ylp[(size_t)l * kDInner] =
        (unsigned short)(__float_as_uint(yv - __uint_as_float(hi)) >> 16);
  }
}

extern "C" void kernel_launch(void* const* d_in, const int* in_sizes, int n_in,
                              void* d_out, int out_size, void* d_ws, size_t ws_size,
                              hipStream_t stream) {
  (void)in_sizes; (void)n_in; (void)out_size; (void)ws_size;
  const float* token     = (const float*)d_in[0];
  const float* in_proj_w = (const float*)d_in[1];
  const float* conv_w    = (const float*)d_in[2];
  const float* conv_b    = (const float*)d_in[3];
  const float* x_proj_w  = (const float*)d_in[4];
  const float* dt_proj_w = (const float*)d_in[5];
  const float* dt_proj_b = (const float*)d_in[6];
  const float* A_log     = (const float*)d_in[7];
  const float* D_skip    = (const float*)d_in[8];
  const float* out_proj_w= (const float*)d_in[9];
  float* out = (float*)d_out;

  float* ws = (float*)d_ws;
  float* xbuf  = ws;                                    // kTok*512 (x, then delta)
  float* zbuf  = xbuf + (size_t)kTok * kDInner;         // kTok*512
  float* xcbuf = zbuf + (size_t)kTok * kDInner;         // kTok*512
  float* dbc   = xcbuf + (size_t)kTok * kDInner;        // kTok*48
  float* ybuf  = dbc + (size_t)kTok * kDbcW;            // kTok*512 multi-use region
  float* hin   = ybuf + (size_t)kTok * kDInner;         // 2M floats
  float* delta = xbuf;

  // ybuf region timeline: [tokH|tokL] during K1  ->  [Pbuf|hloc] S1-S2  ->  [yh|yl] S3-K6
  unsigned short* tokH = (unsigned short*)ybuf;                 // kTok*256 ushorts
  unsigned short* tokL = tokH + (size_t)kTok * kDModel;
  float* Pbuf = ybuf;                                           // 2M floats
  float* hloc = ybuf + (size_t)kB * kG * kDState * kDInner;     // 2M floats
  unsigned short* yh = (unsigned short*)ybuf;                   // kTok*512 ushorts
  unsigned short* yl = yh + (size_t)kTok * kDInner;
  // hin region holds ipH/ipL during K1 (dead before S2 writes hin)
  unsigned short* ipH = (unsigned short*)hin;                   // 1024*256 ushorts
  unsigned short* ipL = ipH + (size_t)2 * kDInner * kDModel;
  // op splits live after hin permanently (+0.5 MB)
  unsigned short* opH = (unsigned short*)(hin + (size_t)kB * kDInner * kG * kDState);
  unsigned short* opL = opH + (size_t)kDModel * kDInner;

  // S0: pre-split fp32 -> bf16 hi/lo (same total bytes as fp32)
  split_k<<<(kTok * kDModel / 4) / 256, 256, 0, stream>>>(token, tokH, tokL,
                                                          kTok * kDModel / 4);
  split_k<<<(2 * kDInner * kDModel / 4) / 256, 256, 0, stream>>>(
      in_proj_w, ipH, ipL, 2 * kDInner * kDModel / 4);
  split_k<<<(kDModel * kDInner / 4) / 256, 256, 0, stream>>>(
      out_proj_w, opH, opL, kDModel * kDInner / 4);

  // K1: xz = token @ in_proj_w^T -> x, z   (pre-split MFMA, global_load_lds)
  {
    dim3 g(kTok / 128, (2 * kDInner) / 64);
    gemm_bt_mfma<1><<<g, 256, 0, stream>>>(tokH, tokL, kDModel, ipH, ipL, kDModel,
                                           xbuf, kDInner, kDModel, zbuf);
  }
  // K2: depthwise conv + silu -> xc
  conv_silu_k<<<(kTok * (kDInner / 4)) / 256, 256, 0, stream>>>(xbuf, conv_w, conv_b, xcbuf);
  // K3: dbc = xc @ x_proj_w^T  (N=48, fp32)
  {
    dim3 g(kTok / 64, 1);
    gemm_bt_f32<0><<<g, 256, 0, stream>>>(xcbuf, kDInner, x_proj_w, kDInner,
                                          dbc, kDbcW, kDbcW, kDInner,
                                          nullptr, nullptr);
  }
  // K4: delta = softplus(dt @ dt_proj_w^T + b)   (K=16, fp32)
  {
    dim3 g(kTok / 64, kDInner / 64);
    gemm_bt_f32<2><<<g, 256, 0, stream>>>(dbc, kDbcW, dt_proj_w, kDtRank,
                                          delta, kDInner, kDInner, kDtRank,
                                          nullptr, dt_proj_b);
  }
  // S1/S2/S3: chunked selective scan (lane = channel); S3 emits y as bf16 hi/lo
  scan_part1<<<(kB * kG * 8) / 4, 256, 0, stream>>>(delta, xcbuf, dbc, A_log,
                                                    Pbuf, hloc);
  scan_part2<<<(kB * kDInner * kDState) / 256, 256, 0, stream>>>(Pbuf, hloc, hin);
  scan_part3<<<(kB * kG * 8) / 4, 256, 0, stream>>>(delta, xcbuf, dbc, zbuf,
                                                    A_log, D_skip, hin, yh, yl);
  // K6: out = y @ out_proj_w^T   (pre-split MFMA, global_load_lds)
  {
    dim3 g(kTok / 128, kDModel / 64);
    gemm_bt_mfma<0><<<g, 256, 0, stream>>>(yh, yl, kDInner, opH, opL, kDInner,
                                           out, kDModel, kDInner, nullptr);
  }
}